// Round 1
// baseline (2172.101 us; speedup 1.0000x reference)
//
#include <hip/hip_runtime.h>
#include <math.h>

#define B_    4
#define H_    64
#define W_    64
#define NPIX  4096   // H_*W_
#define CC    256

// ---------------------------------------------------------------------------
// Stem conv1: [B,3,N] -> relu(W1[64,3] x + b1) -> [B,64,N]
// ---------------------------------------------------------------------------
__global__ __launch_bounds__(256) void stem1_kernel(
    const float* __restrict__ x, const float* __restrict__ w1,
    const float* __restrict__ b1, float* __restrict__ h1) {
    int idx = blockIdx.x * 256 + threadIdx.x;     // b*64*NPIX + o*NPIX + p
    int p = idx & (NPIX - 1);
    int rest = idx >> 12;
    int o = rest & 63;
    int b = rest >> 6;
    const float* xb = x + (size_t)b * 3 * NPIX + p;
    float acc = b1[o];
    acc = fmaf(w1[o * 3 + 0], xb[0],        acc);
    acc = fmaf(w1[o * 3 + 1], xb[NPIX],     acc);
    acc = fmaf(w1[o * 3 + 2], xb[2 * NPIX], acc);
    h1[idx] = fmaxf(acc, 0.f);
}

// ---------------------------------------------------------------------------
// Generic 1x1 conv as GEMM: Out[b,O,N] = act(W[O,Cin] * In[b,Cin,N] + bias)
// grid: (NPIX/64, Cout/64, B), block 256, 64x64 tile, 4x4 micro
// ---------------------------------------------------------------------------
template <int RELU>
__global__ __launch_bounds__(256) void conv1x1_kernel(
    const float* __restrict__ In, const float* __restrict__ Wt,
    const float* __restrict__ bias, float* __restrict__ Out,
    int Cin, int Cout) {
    __shared__ float Ws[16][68];   // [k][m], pad 68 keeps float4-aligned reads
    __shared__ float Is[16][64];   // [k][n]
    int b  = blockIdx.z;
    int m0 = blockIdx.y * 64;
    int p0 = blockIdx.x * 64;
    const float* Ib = In + (size_t)b * Cin * NPIX;
    int tid = threadIdx.x;
    int tx = tid & 15, ty = tid >> 4;
    float acc[4][4] = {};
    for (int k0 = 0; k0 < Cin; k0 += 16) {
        {   // stage W: 64 rows x 16 k, 4 consecutive k per thread
            int i  = tid * 4;
            int m  = i >> 4;
            int kk = i & 15;
            const float* wp = Wt + (size_t)(m0 + m) * Cin + k0 + kk;
            float4 wv = *(const float4*)wp;
            Ws[kk + 0][m] = wv.x; Ws[kk + 1][m] = wv.y;
            Ws[kk + 2][m] = wv.z; Ws[kk + 3][m] = wv.w;
        }
        {   // stage In: 16 k x 64 px
            int i  = tid * 4;
            int kk = i >> 6;
            int j  = i & 63;
            *(float4*)&Is[kk][j] =
                *(const float4*)&Ib[(size_t)(k0 + kk) * NPIX + p0 + j];
        }
        __syncthreads();
        #pragma unroll
        for (int kk = 0; kk < 16; ++kk) {
            float a[4], bb[4];
            *(float4*)a  = *(const float4*)&Ws[kk][ty * 4];
            *(float4*)bb = *(const float4*)&Is[kk][tx * 4];
            #pragma unroll
            for (int i = 0; i < 4; ++i)
                #pragma unroll
                for (int j = 0; j < 4; ++j)
                    acc[i][j] = fmaf(a[i], bb[j], acc[i][j]);
        }
        __syncthreads();
    }
    float* Ob = Out + (size_t)b * Cout * NPIX;
    #pragma unroll
    for (int i = 0; i < 4; ++i) {
        int m = m0 + ty * 4 + i;
        float bv = bias[m];
        float4 r;
        r.x = acc[i][0] + bv; r.y = acc[i][1] + bv;
        r.z = acc[i][2] + bv; r.w = acc[i][3] + bv;
        if (RELU) {
            r.x = fmaxf(r.x, 0.f); r.y = fmaxf(r.y, 0.f);
            r.z = fmaxf(r.z, 0.f); r.w = fmaxf(r.w, 0.f);
        }
        *(float4*)&Ob[(size_t)m * NPIX + p0 + tx * 4] = r;
    }
}

// ---------------------------------------------------------------------------
// 3x3 SAME conv: Out[b,o,h,w] = act(sum_{c,ky,kx} W[o,c,ky,kx] In[b,c,h+ky-1,w+kx-1] + bias)
// grid: (H_=64 rows, Cout/64=4, B), block 256. Tile: 64 out-ch x one image row.
// ---------------------------------------------------------------------------
__global__ __launch_bounds__(256) void conv3x3_kernel(
    const float* __restrict__ In, const float* __restrict__ Wt,
    const float* __restrict__ bias, float* __restrict__ Out, int relu) {
    __shared__ float Bs[16][3][66];    // [c][row(-1,0,+1)][1+64+1 zero-padded]
    __shared__ float Wsh[16][9][65];   // [c][tap][o], pad 65 (scalar reads, bank-clean stores)
    int b  = blockIdx.z;
    int o0 = blockIdx.y * 64;
    int h  = blockIdx.x;
    int tid = threadIdx.x, tx = tid & 15, ty = tid >> 4;
    const float* Ib = In + (size_t)b * CC * NPIX;
    float acc[4][4] = {};
    for (int c0 = 0; c0 < CC; c0 += 16) {
        // stage 3 input rows for 16 channels (zero at dy borders)
        #pragma unroll
        for (int t = 0; t < 12; ++t) {
            int idx = tid + t * 256;          // 0..3071
            int cc  = idx / 192;
            int rem = idx - cc * 192;
            int r   = rem >> 6;
            int w   = rem & 63;
            int hh  = h - 1 + r;
            float val = 0.f;
            if (hh >= 0 && hh < H_)
                val = Ib[((size_t)(c0 + cc) * H_ + hh) * W_ + w];
            Bs[cc][r][w + 1] = val;
        }
        if (tid < 96) {                       // zero side pads
            int cc = tid / 6; int rem = tid % 6;
            int r = rem >> 1; int side = rem & 1;
            Bs[cc][r][side ? 65 : 0] = 0.f;
        }
        // stage weights: 64 o x 16 c x 9 taps
        #pragma unroll
        for (int t = 0; t < 36; ++t) {
            int idx = tid + t * 256;          // 0..9215
            int o   = idx / 144;
            int rem = idx - o * 144;
            int cc  = rem / 9;
            int tap = rem - cc * 9;
            Wsh[cc][tap][o] = Wt[((size_t)(o0 + o) * CC + (c0 + cc)) * 9 + tap];
        }
        __syncthreads();
        #pragma unroll
        for (int cc = 0; cc < 16; ++cc) {
            float bv[3][6];
            #pragma unroll
            for (int r = 0; r < 3; ++r)
                #pragma unroll
                for (int j = 0; j < 6; ++j)
                    bv[r][j] = Bs[cc][r][tx * 4 + j];
            #pragma unroll
            for (int ky = 0; ky < 3; ++ky) {
                #pragma unroll
                for (int kx = 0; kx < 3; ++kx) {
                    int tap = ky * 3 + kx;
                    float w4[4];
                    #pragma unroll
                    for (int i = 0; i < 4; ++i) w4[i] = Wsh[cc][tap][ty * 4 + i];
                    #pragma unroll
                    for (int i = 0; i < 4; ++i)
                        #pragma unroll
                        for (int j = 0; j < 4; ++j)
                            acc[i][j] = fmaf(w4[i], bv[ky][j + kx], acc[i][j]);
                }
            }
        }
        __syncthreads();
    }
    #pragma unroll
    for (int i = 0; i < 4; ++i) {
        int o = o0 + ty * 4 + i;
        float bb = bias[o];
        float4 r;
        r.x = acc[i][0] + bb; r.y = acc[i][1] + bb;
        r.z = acc[i][2] + bb; r.w = acc[i][3] + bb;
        if (relu) {
            r.x = fmaxf(r.x, 0.f); r.y = fmaxf(r.y, 0.f);
            r.z = fmaxf(r.z, 0.f); r.w = fmaxf(r.w, 0.f);
        }
        *(float4*)&Out[((size_t)b * CC + o) * NPIX + (size_t)h * W_ + tx * 4] = r;
    }
}

// ---------------------------------------------------------------------------
// S[n,m] = sum_c K[b,c,n] * Q[b,c,m]    grid: (NPIX/64 m, NPIX/64 n, nb)
// ---------------------------------------------------------------------------
__global__ __launch_bounds__(256) void sgemm_kernel(
    const float* __restrict__ K, const float* __restrict__ Q,
    float* __restrict__ S, int b0, size_t sStride) {
    __shared__ float Ks[16][64];
    __shared__ float Qs[16][64];
    int b  = b0 + blockIdx.z;
    int n0 = blockIdx.y * 64;
    int m0 = blockIdx.x * 64;
    const float* Kb = K + (size_t)b * CC * NPIX;
    const float* Qb = Q + (size_t)b * CC * NPIX;
    float* Sb = S + (size_t)blockIdx.z * sStride;
    int tid = threadIdx.x, tx = tid & 15, ty = tid >> 4;
    float acc[4][4] = {};
    for (int k0 = 0; k0 < CC; k0 += 16) {
        int i  = tid * 4;
        int kk = i >> 6;
        int j  = i & 63;
        *(float4*)&Ks[kk][j] = *(const float4*)&Kb[(size_t)(k0 + kk) * NPIX + n0 + j];
        *(float4*)&Qs[kk][j] = *(const float4*)&Qb[(size_t)(k0 + kk) * NPIX + m0 + j];
        __syncthreads();
        #pragma unroll
        for (int kk2 = 0; kk2 < 16; ++kk2) {
            float a[4], bb[4];
            *(float4*)a  = *(const float4*)&Ks[kk2][ty * 4];
            *(float4*)bb = *(const float4*)&Qs[kk2][tx * 4];
            #pragma unroll
            for (int i2 = 0; i2 < 4; ++i2)
                #pragma unroll
                for (int j2 = 0; j2 < 4; ++j2)
                    acc[i2][j2] = fmaf(a[i2], bb[j2], acc[i2][j2]);
        }
        __syncthreads();
    }
    #pragma unroll
    for (int i = 0; i < 4; ++i)
        *(float4*)&Sb[(size_t)(n0 + ty * 4 + i) * NPIX + m0 + tx * 4] =
            *(float4*)&acc[i][0];
}

// ---------------------------------------------------------------------------
// Row softmax in place over last dim. grid: (NPIX rows, nb), block 256.
// ---------------------------------------------------------------------------
__global__ __launch_bounds__(256) void softmax_kernel(
    float* __restrict__ S, size_t sStride) {
    __shared__ float smax[4], ssum[4];
    float* row = S + (size_t)blockIdx.y * sStride + (size_t)blockIdx.x * NPIX;
    int tid = threadIdx.x;
    float4* rp = (float4*)row;
    float4 v[4];
    float m = -1e30f;
    #pragma unroll
    for (int r = 0; r < 4; ++r) {
        v[r] = rp[r * 256 + tid];
        m = fmaxf(m, fmaxf(fmaxf(v[r].x, v[r].y), fmaxf(v[r].z, v[r].w)));
    }
    #pragma unroll
    for (int off = 32; off; off >>= 1) m = fmaxf(m, __shfl_xor(m, off, 64));
    if ((tid & 63) == 0) smax[tid >> 6] = m;
    __syncthreads();
    m = fmaxf(fmaxf(smax[0], smax[1]), fmaxf(smax[2], smax[3]));
    float s = 0.f;
    #pragma unroll
    for (int r = 0; r < 4; ++r) {
        v[r].x = expf(v[r].x - m); v[r].y = expf(v[r].y - m);
        v[r].z = expf(v[r].z - m); v[r].w = expf(v[r].w - m);
        s += (v[r].x + v[r].y) + (v[r].z + v[r].w);
    }
    #pragma unroll
    for (int off = 32; off; off >>= 1) s += __shfl_xor(s, off, 64);
    if ((tid & 63) == 0) ssum[tid >> 6] = s;
    __syncthreads();
    s = (ssum[0] + ssum[1]) + (ssum[2] + ssum[3]);
    float inv = 1.0f / s;
    #pragma unroll
    for (int r = 0; r < 4; ++r) {
        v[r].x *= inv; v[r].y *= inv; v[r].z *= inv; v[r].w *= inv;
        rp[r * 256 + tid] = v[r];
    }
}

// ---------------------------------------------------------------------------
// Out[b,c,m] = alpha*CV[b,c,m] + beta * sum_n V[b,c,n] P[n,m]
// grid: (NPIX/64 m, CC/64 c, nb)
// ---------------------------------------------------------------------------
__global__ __launch_bounds__(256) void pv_kernel(
    const float* __restrict__ V, const float* __restrict__ P,
    const float* __restrict__ CV, const float* __restrict__ alphaP,
    const float* __restrict__ betaP, float* __restrict__ out,
    int b0, size_t sStride) {
    __shared__ float As[16][68];   // [k][c] (transposed V tile), float4-aligned reads
    __shared__ float Bs[16][64];   // [k][m]
    int b  = b0 + blockIdx.z;
    int c0 = blockIdx.y * 64;
    int m0 = blockIdx.x * 64;
    const float* Vb = V + (size_t)b * CC * NPIX;
    const float* Pb = P + (size_t)blockIdx.z * sStride;
    int tid = threadIdx.x, tx = tid & 15, ty = tid >> 4;
    float acc[4][4] = {};
    for (int k0 = 0; k0 < NPIX; k0 += 16) {
        {   // stage V^T
            int ci = tid >> 2;
            int kq = (tid & 3) * 4;
            float4 av = *(const float4*)&Vb[(size_t)(c0 + ci) * NPIX + k0 + kq];
            As[kq + 0][ci] = av.x; As[kq + 1][ci] = av.y;
            As[kq + 2][ci] = av.z; As[kq + 3][ci] = av.w;
        }
        {   // stage P
            int i  = tid * 4;
            int kk = i >> 6;
            int j  = i & 63;
            *(float4*)&Bs[kk][j] = *(const float4*)&Pb[(size_t)(k0 + kk) * NPIX + m0 + j];
        }
        __syncthreads();
        #pragma unroll
        for (int kk = 0; kk < 16; ++kk) {
            float a[4], bb[4];
            *(float4*)a  = *(const float4*)&As[kk][ty * 4];
            *(float4*)bb = *(const float4*)&Bs[kk][tx * 4];
            #pragma unroll
            for (int i = 0; i < 4; ++i)
                #pragma unroll
                for (int j = 0; j < 4; ++j)
                    acc[i][j] = fmaf(a[i], bb[j], acc[i][j]);
        }
        __syncthreads();
    }
    float a = alphaP[0], be = betaP[0];
    #pragma unroll
    for (int i = 0; i < 4; ++i) {
        int c = c0 + ty * 4 + i;
        size_t base = ((size_t)b * CC + c) * NPIX + m0 + tx * 4;
        float4 cvv = *(const float4*)&CV[base];
        float4 r;
        r.x = a * cvv.x + be * acc[i][0];
        r.y = a * cvv.y + be * acc[i][1];
        r.z = a * cvv.z + be * acc[i][2];
        r.w = a * cvv.w + be * acc[i][3];
        *(float4*)&out[base] = r;
    }
}

// ---------------------------------------------------------------------------
extern "C" void kernel_launch(void* const* d_in, const int* in_sizes, int n_in,
                              void* d_out, int out_size, void* d_ws, size_t ws_size,
                              hipStream_t stream) {
    const float* x   = (const float*)d_in[0];
    const float* w1  = (const float*)d_in[1];  const float* b1  = (const float*)d_in[2];
    const float* w2  = (const float*)d_in[3];  const float* b2  = (const float*)d_in[4];
    const float* w3  = (const float*)d_in[5];  const float* b3  = (const float*)d_in[6];
    const float* wb1 = (const float*)d_in[7];  const float* bb1 = (const float*)d_in[8];
    const float* wb2 = (const float*)d_in[9];  const float* bb2 = (const float*)d_in[10];
    const float* wq  = (const float*)d_in[11]; const float* bq  = (const float*)d_in[12];
    const float* wk  = (const float*)d_in[13]; const float* bk  = (const float*)d_in[14];
    const float* wv  = (const float*)d_in[15]; const float* bv  = (const float*)d_in[16];
    const float* alpha = (const float*)d_in[17];
    const float* beta  = (const float*)d_in[18];

    float* ws  = (float*)d_ws;
    const size_t BUF = (size_t)B_ * CC * NPIX;   // 4,194,304 floats
    float* x3  = ws;
    float* qb  = ws + 1 * BUF;
    float* kb  = ws + 2 * BUF;
    float* vb  = ws + 3 * BUF;
    float* t1  = ws + 4 * BUF;
    float* cv  = ws + 5 * BUF;
    float* Sb  = ws + 6 * BUF;
    float* out = (float*)d_out;
    float* h1  = qb;   // overlay: consumed before q is written
    float* h2  = kb;   // overlay: consumed before k is written

    // stem
    stem1_kernel<<<dim3((B_ * 64 * NPIX) / 256), 256, 0, stream>>>(x, w1, b1, h1);
    conv1x1_kernel<1><<<dim3(64, 2, B_), 256, 0, stream>>>(h1, w2, b2, h2, 64, 128);
    conv1x1_kernel<1><<<dim3(64, 4, B_), 256, 0, stream>>>(h2, w3, b3, x3, 128, 256);
    // q, k, v
    conv1x1_kernel<0><<<dim3(64, 4, B_), 256, 0, stream>>>(x3, wq, bq, qb, 256, 256);
    conv1x1_kernel<0><<<dim3(64, 4, B_), 256, 0, stream>>>(x3, wk, bk, kb, 256, 256);
    conv1x1_kernel<0><<<dim3(64, 4, B_), 256, 0, stream>>>(x3, wv, bv, vb, 256, 256);
    // conv branch
    conv3x3_kernel<<<dim3(H_, 4, B_), 256, 0, stream>>>(x3, wb1, bb1, t1, 1);
    conv3x3_kernel<<<dim3(H_, 4, B_), 256, 0, stream>>>(t1, wb2, bb2, cv, 0);

    // attention: materialize P per resident batch group
    const size_t SSTRIDE = (size_t)NPIX * NPIX;               // 16,777,216 floats
    const size_t needBig = (6 * BUF + 4 * SSTRIDE) * 4;       // ~369 MB
    int nb = (ws_size >= needBig) ? 4 : 1;
    for (int b0 = 0; b0 < B_; b0 += nb) {
        sgemm_kernel<<<dim3(64, 64, nb), 256, 0, stream>>>(kb, qb, Sb, b0, SSTRIDE);
        softmax_kernel<<<dim3(NPIX, nb), 256, 0, stream>>>(Sb, SSTRIDE);
        pv_kernel<<<dim3(64, 4, nb), 256, 0, stream>>>(vb, Sb, cv, alpha, beta, out, b0, SSTRIDE);
    }
}

// Round 2
// 439.457 us; speedup vs baseline: 4.9427x; 4.9427x over previous
//
#include <hip/hip_runtime.h>
#include <math.h>

#define NPIX 4096
#define CC   256

typedef __attribute__((ext_vector_type(8))) short bf16x8;
typedef __attribute__((ext_vector_type(4))) float f32x4;

__device__ inline unsigned short f2bf(float f) {
    unsigned u = __builtin_bit_cast(unsigned, f);
    u += 0x7FFF + ((u >> 16) & 1);              // RTN-E
    return (unsigned short)(u >> 16);
}
__device__ inline float bf2f(unsigned short h) {
    unsigned u = (unsigned)h << 16;
    return __builtin_bit_cast(float, u);
}

// ---------------------------------------------------------------------------
// Weight prep: fp32 -> bf16; 3x3 weights reordered [O][C][3][3] -> [O][tap][C]
// ---------------------------------------------------------------------------
__global__ __launch_bounds__(256) void prep_kernel(
    const float* __restrict__ w2, const float* __restrict__ w3,
    const float* __restrict__ wq, const float* __restrict__ wk,
    const float* __restrict__ wv, const float* __restrict__ wb1,
    const float* __restrict__ wb2,
    unsigned short* w2b, unsigned short* w3b, unsigned short* wqb,
    unsigned short* wkb, unsigned short* wvb,
    unsigned short* wr1, unsigned short* wr2) {
    int i = blockIdx.x * 256 + threadIdx.x;
    if (i < 8192)  w2b[i] = f2bf(w2[i]);
    if (i < 32768) w3b[i] = f2bf(w3[i]);
    if (i < 65536) { wqb[i] = f2bf(wq[i]); wkb[i] = f2bf(wk[i]); wvb[i] = f2bf(wv[i]); }
    if (i < 589824) {
        int o = i / 2304; int r = i - o * 2304; int tap = r >> 8; int c = r & 255;
        wr1[i] = f2bf(wb1[(o * 256 + c) * 9 + tap]);
        wr2[i] = f2bf(wb2[(o * 256 + c) * 9 + tap]);
    }
}

// ---------------------------------------------------------------------------
// Stem: x[b,3,p] fp32 -> h1T[b,p,64] bf16 (pixel-major), relu
// ---------------------------------------------------------------------------
__global__ __launch_bounds__(256) void stem1_kernel(
    const float* __restrict__ x, const float* __restrict__ w1,
    const float* __restrict__ b1, unsigned short* __restrict__ h1T) {
    int idx = blockIdx.x * 256 + threadIdx.x;   // b*2^18 + p*64 + o
    int o = idx & 63;
    int p = (idx >> 6) & 4095;
    int b = idx >> 18;
    const float* xb = x + (size_t)b * 3 * NPIX + p;
    float acc = b1[o];
    acc = fmaf(w1[o * 3 + 0], xb[0],        acc);
    acc = fmaf(w1[o * 3 + 1], xb[NPIX],     acc);
    acc = fmaf(w1[o * 3 + 2], xb[2 * NPIX], acc);
    h1T[idx] = f2bf(fmaxf(acc, 0.f));
}

// ---------------------------------------------------------------------------
// Unified bf16 MFMA GEMM: D[row][col] = sum_k A[row][k] * BT[col][k]
// 128x128 tile, BK=64, 4 waves (2x2), wave tile 64x64 (4x4 16x16x32 frags).
// EPI: 0 = bf16 store (S-GEMM)
//      1 = bf16, +bias[col], relu     (pixel-major 1x1 conv)
//      2 = bf16, +bias[col]           (q,k)
//      3 = bf16, +bias[row]           (v, channel-major)
//      4 = f32,  alpha*CV + beta*acc  (PV + final combine)
// ---------------------------------------------------------------------------
template<int EPI>
__global__ __launch_bounds__(256) void gemm_bf16(
    const unsigned short* __restrict__ A, long lda, long sA,
    const unsigned short* __restrict__ BT, long ldb, long sB,
    int K,
    void* __restrict__ Cp, long ldc, long sC,
    const float* __restrict__ bias,
    const float* __restrict__ CV,
    const float* __restrict__ alphaP, const float* __restrict__ betaP) {
    constexpr int LDK = 72;                     // 64 + 8 pad (bank-quad spread)
    __shared__ unsigned short As[128 * LDK];
    __shared__ unsigned short Bs[128 * LDK];
    const int tid  = threadIdx.x;
    const int lane = tid & 63;
    const int wave = tid >> 6;
    const int wr = (wave >> 1) * 64, wc = (wave & 1) * 64;
    const int l15 = lane & 15, lh = lane >> 4;
    const int z = blockIdx.z;
    const unsigned short* Ab = A  + (size_t)z * sA + (size_t)blockIdx.y * 128 * lda;
    const unsigned short* Bb = BT + (size_t)z * sB + (size_t)blockIdx.x * 128 * ldb;

    f32x4 acc[4][4];
    #pragma unroll
    for (int i = 0; i < 4; ++i)
        #pragma unroll
        for (int j = 0; j < 4; ++j) { f32x4 zr = {0.f, 0.f, 0.f, 0.f}; acc[i][j] = zr; }

    for (int k0 = 0; k0 < K; k0 += 64) {
        #pragma unroll
        for (int t = 0; t < 4; ++t) {           // 1024 16B chunks per tile
            int q = t * 256 + tid;
            int r = q >> 3, c = (q & 7) * 8;
            *(int4*)&As[r * LDK + c] = *(const int4*)&Ab[(size_t)r * lda + k0 + c];
            *(int4*)&Bs[r * LDK + c] = *(const int4*)&Bb[(size_t)r * ldb + k0 + c];
        }
        __syncthreads();
        #pragma unroll
        for (int ks = 0; ks < 2; ++ks) {
            bf16x8 a[4], b[4];
            #pragma unroll
            for (int f = 0; f < 4; ++f) {
                a[f] = *(const bf16x8*)&As[(wr + f * 16 + l15) * LDK + ks * 32 + lh * 8];
                b[f] = *(const bf16x8*)&Bs[(wc + f * 16 + l15) * LDK + ks * 32 + lh * 8];
            }
            #pragma unroll
            for (int i = 0; i < 4; ++i)
                #pragma unroll
                for (int j = 0; j < 4; ++j)
                    acc[i][j] = __builtin_amdgcn_mfma_f32_16x16x32_bf16(
                        a[i], b[j], acc[i][j], 0, 0, 0);
        }
        __syncthreads();
    }

    const int row0 = blockIdx.y * 128 + wr;
    const int col0 = blockIdx.x * 128 + wc;
    if (EPI == 4) {
        float* OUT = (float*)Cp + (size_t)z * sC;
        const float* CVb = CV + (size_t)z * sC;
        const float al = alphaP[0], be = betaP[0];
        #pragma unroll
        for (int i = 0; i < 4; ++i)
            #pragma unroll
            for (int j = 0; j < 4; ++j) {
                int cgl = col0 + j * 16 + l15;
                #pragma unroll
                for (int q = 0; q < 4; ++q) {
                    int r = row0 + i * 16 + lh * 4 + q;
                    size_t o = (size_t)r * ldc + cgl;
                    OUT[o] = al * CVb[o] + be * acc[i][j][q];
                }
            }
    } else {
        unsigned short* OUT = (unsigned short*)Cp + (size_t)z * sC;
        #pragma unroll
        for (int i = 0; i < 4; ++i)
            #pragma unroll
            for (int j = 0; j < 4; ++j) {
                int cgl = col0 + j * 16 + l15;
                float bc = (EPI == 1 || EPI == 2) ? bias[cgl] : 0.f;
                #pragma unroll
                for (int q = 0; q < 4; ++q) {
                    int r = row0 + i * 16 + lh * 4 + q;
                    float v = acc[i][j][q];
                    if (EPI == 3) v += bias[r];
                    else if (EPI == 1 || EPI == 2) v += bc;
                    if (EPI == 1) v = fmaxf(v, 0.f);
                    OUT[(size_t)r * ldc + cgl] = f2bf(v);
                }
            }
    }
}

// ---------------------------------------------------------------------------
// 3x3 SAME conv as implicit MFMA GEMM. Input X pixel-major [b][4096][256] bf16.
// Block: 128 output channels (blockIdx.y) x 128 pixels (2 image rows, blockIdx.x).
// K = 9 taps x 256 c, chunked (tap, 64c). Wr = [256][9][256] bf16.
// PIXOUT=1: out bf16 pixel-major [p][256], relu (branch conv #1)
// PIXOUT=0: out fp32 channel-major [256][p], no relu (branch conv #2)
// ---------------------------------------------------------------------------
template<int PIXOUT>
__global__ __launch_bounds__(256) void conv3_bf16(
    const unsigned short* __restrict__ X, const unsigned short* __restrict__ Wr,
    const float* __restrict__ bias, void* __restrict__ Outp) {
    __shared__ unsigned short patch[264 * 72];  // 4 rows x 66 cols x 64c (padded)
    __shared__ unsigned short wt[128 * 72];     // 128 o x 64 c
    const int tid  = threadIdx.x;
    const int lane = tid & 63;
    const int wave = tid >> 6;
    const int l15 = lane & 15, lh = lane >> 4;
    const int h0 = blockIdx.x;                  // pixel rows 2h0, 2h0+1
    const int oh = blockIdx.y;                  // o half
    const int b  = blockIdx.z;
    const int wy = (wave >> 1) * 64, wx = (wave & 1) * 64;
    const int obase = PIXOUT ? wx : wy;
    const int pbase = PIXOUT ? wy : wx;
    const unsigned short* Xb  = X + (size_t)b * (NPIX * CC);
    const unsigned short* Wro = Wr + (size_t)oh * 128 * 2304;

    f32x4 acc[4][4];
    #pragma unroll
    for (int i = 0; i < 4; ++i)
        #pragma unroll
        for (int j = 0; j < 4; ++j) { f32x4 zr = {0.f, 0.f, 0.f, 0.f}; acc[i][j] = zr; }

    for (int cc0 = 0; cc0 < 256; cc0 += 64) {
        __syncthreads();                        // patch readers done
        #pragma unroll
        for (int t = 0; t < 9; ++t) {           // 264 slots x 8 chunks = 2112
            int q = t * 256 + tid;
            if (q < 2112) {
                int s = q >> 3, ch = (q & 7) * 8;
                int r = s / 66, w = s - r * 66;
                int hh = h0 * 2 - 1 + r, ww = w - 1;
                int4 v = make_int4(0, 0, 0, 0);
                if ((unsigned)hh < 64u && (unsigned)ww < 64u)
                    v = *(const int4*)&Xb[(size_t)(hh * 64 + ww) * 256 + cc0 + ch];
                *(int4*)&patch[s * 72 + ch] = v;
            }
        }
        for (int tap = 0; tap < 9; ++tap) {
            const int dy = tap / 3 - 1, dx = tap % 3 - 1;
            __syncthreads();                    // wt readers done / patch ready
            #pragma unroll
            for (int t = 0; t < 4; ++t) {       // 128 o x 8 chunks
                int q = t * 256 + tid;
                int o = q >> 3, ch = (q & 7) * 8;
                *(int4*)&wt[o * 72 + ch] =
                    *(const int4*)&Wro[(size_t)o * 2304 + tap * 256 + cc0 + ch];
            }
            __syncthreads();
            #pragma unroll
            for (int ks = 0; ks < 2; ++ks) {
                bf16x8 wf[4], pf[4];
                #pragma unroll
                for (int f = 0; f < 4; ++f) {
                    int o = obase + f * 16 + l15;
                    wf[f] = *(const bf16x8*)&wt[o * 72 + ks * 32 + lh * 8];
                    int p = pbase + f * 16 + l15;
                    int slot = ((p >> 6) + dy + 1) * 66 + (p & 63) + dx + 1;
                    pf[f] = *(const bf16x8*)&patch[slot * 72 + ks * 32 + lh * 8];
                }
                #pragma unroll
                for (int i = 0; i < 4; ++i)
                    #pragma unroll
                    for (int j = 0; j < 4; ++j) {
                        if (PIXOUT)
                            acc[i][j] = __builtin_amdgcn_mfma_f32_16x16x32_bf16(
                                pf[i], wf[j], acc[i][j], 0, 0, 0);
                        else
                            acc[i][j] = __builtin_amdgcn_mfma_f32_16x16x32_bf16(
                                wf[i], pf[j], acc[i][j], 0, 0, 0);
                    }
            }
        }
    }

    const int P0 = h0 * 128;
    if (PIXOUT) {
        unsigned short* O = (unsigned short*)Outp + (size_t)b * (NPIX * CC);
        #pragma unroll
        for (int i = 0; i < 4; ++i)
            #pragma unroll
            for (int j = 0; j < 4; ++j) {
                int o = oh * 128 + obase + j * 16 + l15;
                float bb = bias[o];
                #pragma unroll
                for (int q = 0; q < 4; ++q) {
                    int p = pbase + i * 16 + lh * 4 + q;
                    float v = fmaxf(acc[i][j][q] + bb, 0.f);
                    O[(size_t)(P0 + p) * CC + o] = f2bf(v);
                }
            }
    } else {
        float* O = (float*)Outp + (size_t)b * (CC * NPIX);
        #pragma unroll
        for (int i = 0; i < 4; ++i)
            #pragma unroll
            for (int j = 0; j < 4; ++j) {
                #pragma unroll
                for (int q = 0; q < 4; ++q) {
                    int o = oh * 128 + obase + i * 16 + lh * 4 + q;
                    int p = pbase + j * 16 + l15;
                    O[(size_t)o * NPIX + P0 + p] = acc[i][j][q] + bias[o];
                }
            }
    }
}

// ---------------------------------------------------------------------------
// Column softmax on S^T [4096 m][4096 n] bf16, in place (axis = m, per column n).
// Block: 64 columns. Pass 1: online max/sum. Pass 2: write exp(x-M)/S.
// ---------------------------------------------------------------------------
__global__ __launch_bounds__(256) void softmax_kernel(unsigned short* __restrict__ S,
                                                      long SS) {
    __shared__ float red_m[4][16][4];
    __shared__ float red_s[4][16][4];
    unsigned short* Sb = S + (size_t)blockIdx.y * SS;
    const int tid  = threadIdx.x;
    const int lane = tid & 63;
    const int wave = tid >> 6;
    const int cg = tid & 15;
    const int mg = tid >> 4;
    const size_t colbase = (size_t)blockIdx.x * 64 + cg * 4;

    float mx[4] = {-1e30f, -1e30f, -1e30f, -1e30f};
    float sm[4] = {0.f, 0.f, 0.f, 0.f};
    for (int i = 0; i < 256; ++i) {
        int m = mg + i * 16;
        ushort4 u = *(const ushort4*)&Sb[(size_t)m * 4096 + colbase];
        float xs[4] = {bf2f(u.x), bf2f(u.y), bf2f(u.z), bf2f(u.w)};
        #pragma unroll
        for (int j = 0; j < 4; ++j) {
            float xv = xs[j];
            if (xv > mx[j]) { sm[j] *= __expf(mx[j] - xv); mx[j] = xv; }
            sm[j] += __expf(xv - mx[j]);
        }
    }
    #pragma unroll
    for (int off = 16; off <= 32; off <<= 1) {
        #pragma unroll
        for (int j = 0; j < 4; ++j) {
            float om = __shfl_xor(mx[j], off);
            float os = __shfl_xor(sm[j], off);
            float mn = fmaxf(mx[j], om);
            sm[j] = sm[j] * __expf(mx[j] - mn) + os * __expf(om - mn);
            mx[j] = mn;
        }
    }
    if (lane < 16) {
        #pragma unroll
        for (int j = 0; j < 4; ++j) { red_m[wave][lane][j] = mx[j]; red_s[wave][lane][j] = sm[j]; }
    }
    __syncthreads();
    float M[4], I[4];
    #pragma unroll
    for (int j = 0; j < 4; ++j) {
        float m0 = red_m[0][cg][j], s0 = red_s[0][cg][j];
        #pragma unroll
        for (int wv = 1; wv < 4; ++wv) {
            float m1 = red_m[wv][cg][j], s1 = red_s[wv][cg][j];
            float mn = fmaxf(m0, m1);
            s0 = s0 * __expf(m0 - mn) + s1 * __expf(m1 - mn);
            m0 = mn;
        }
        M[j] = m0; I[j] = 1.f / s0;
    }
    for (int i = 0; i < 256; ++i) {
        int m = mg + i * 16;
        size_t off = (size_t)m * 4096 + colbase;
        ushort4 u = *(const ushort4*)&Sb[off];
        ushort4 o;
        o.x = f2bf(__expf(bf2f(u.x) - M[0]) * I[0]);
        o.y = f2bf(__expf(bf2f(u.y) - M[1]) * I[1]);
        o.z = f2bf(__expf(bf2f(u.z) - M[2]) * I[2]);
        o.w = f2bf(__expf(bf2f(u.w) - M[3]) * I[3]);
        *(ushort4*)&Sb[off] = o;
    }
}

// ---------------------------------------------------------------------------
extern "C" void kernel_launch(void* const* d_in, const int* in_sizes, int n_in,
                              void* d_out, int out_size, void* d_ws, size_t ws_size,
                              hipStream_t stream) {
    const float* x   = (const float*)d_in[0];
    const float* w1  = (const float*)d_in[1];  const float* b1  = (const float*)d_in[2];
    const float* w2  = (const float*)d_in[3];  const float* b2  = (const float*)d_in[4];
    const float* w3  = (const float*)d_in[5];  const float* b3  = (const float*)d_in[6];
    const float* wb1 = (const float*)d_in[7];  const float* bb1 = (const float*)d_in[8];
    const float* wb2 = (const float*)d_in[9];  const float* bb2 = (const float*)d_in[10];
    const float* wq  = (const float*)d_in[11]; const float* bq  = (const float*)d_in[12];
    const float* wk  = (const float*)d_in[13]; const float* bk  = (const float*)d_in[14];
    const float* wv  = (const float*)d_in[15]; const float* bv  = (const float*)d_in[16];
    const float* alpha = (const float*)d_in[17];
    const float* beta  = (const float*)d_in[18];

    const size_t MB = 1 << 20;
    char* wsb = (char*)d_ws;
    unsigned short* h1T = (unsigned short*)(wsb + 0 * MB);   // [4][4096][64]
    unsigned short* h2T = (unsigned short*)(wsb + 2 * MB);   // [4][4096][128]
    unsigned short* x3T = (unsigned short*)(wsb + 6 * MB);   // [4][4096][256]
    unsigned short* qT  = (unsigned short*)(wsb + 14 * MB);  // [4][4096][256]
    unsigned short* kT  = (unsigned short*)(wsb + 22 * MB);  // [4][4096][256]
    unsigned short* vB  = (unsigned short*)(wsb + 30 * MB);  // [4][256][4096]
    unsigned short* t1T = (unsigned short*)(wsb + 38 * MB);  // [4][4096][256]
    float*          cv  = (float*)(wsb + 46 * MB);           // [4][256][4096] fp32
    unsigned short* w2b = (unsigned short*)(wsb + 62 * MB);
    unsigned short* w3b = w2b + 8192;
    unsigned short* wqb = w3b + 32768;
    unsigned short* wkb = wqb + 65536;
    unsigned short* wvb = wkb + 65536;
    unsigned short* wr1 = wvb + 65536;
    unsigned short* wr2 = wr1 + 589824;
    unsigned short* ST  = (unsigned short*)(wsb + 66 * MB);  // [nb][4096][4096]
    float* out = (float*)d_out;

    prep_kernel<<<2304, 256, 0, stream>>>(w2, w3, wq, wk, wv, wb1, wb2,
                                          w2b, w3b, wqb, wkb, wvb, wr1, wr2);
    stem1_kernel<<<4096, 256, 0, stream>>>(x, w1, b1, h1T);

    // conv2: h1T[4096][64] x w2b -> h2T[4096][128], relu
    gemm_bf16<1><<<dim3(1, 32, 4), 256, 0, stream>>>(
        h1T, 64, 4096L * 64, w2b, 64, 0, 64,
        h2T, 128, 4096L * 128, b2, nullptr, nullptr, nullptr);
    // conv3: -> x3T[4096][256], relu
    gemm_bf16<1><<<dim3(2, 32, 4), 256, 0, stream>>>(
        h2T, 128, 4096L * 128, w3b, 128, 0, 128,
        x3T, 256, 4096L * 256, b3, nullptr, nullptr, nullptr);
    // q, k (pixel-major)
    gemm_bf16<2><<<dim3(2, 32, 4), 256, 0, stream>>>(
        x3T, 256, 4096L * 256, wqb, 256, 0, 256,
        qT, 256, 4096L * 256, bq, nullptr, nullptr, nullptr);
    gemm_bf16<2><<<dim3(2, 32, 4), 256, 0, stream>>>(
        x3T, 256, 4096L * 256, wkb, 256, 0, 256,
        kT, 256, 4096L * 256, bk, nullptr, nullptr, nullptr);
    // v (channel-major): A = wvb [256][256] (sA=0), BT = x3T
    gemm_bf16<3><<<dim3(32, 2, 4), 256, 0, stream>>>(
        wvb, 256, 0, x3T, 256, 4096L * 256, 256,
        vB, 4096, 256L * 4096, bv, nullptr, nullptr, nullptr);
    // conv3x3 branch
    conv3_bf16<1><<<dim3(32, 2, 4), 256, 0, stream>>>(x3T, wr1, bb1, t1T);
    conv3_bf16<0><<<dim3(32, 2, 4), 256, 0, stream>>>(t1T, wr2, bb2, cv);

    // attention: S^T = Q.K^T -> column softmax -> out = alpha*cv + beta*V.P
    const long SS = 4096L * 4096;
    const size_t base = 66 * MB;
    int nb = 1;
    if (ws_size >= base + 4 * (size_t)SS * 2)      nb = 4;
    else if (ws_size >= base + 2 * (size_t)SS * 2) nb = 2;
    for (int b0 = 0; b0 < 4; b0 += nb) {
        gemm_bf16<0><<<dim3(32, 32, nb), 256, 0, stream>>>(
            qT + (size_t)b0 * 4096 * 256, 256, 4096L * 256,
            kT + (size_t)b0 * 4096 * 256, 256, 4096L * 256,
            256, ST, 4096, SS, nullptr, nullptr, nullptr, nullptr);
        softmax_kernel<<<dim3(64, nb), 256, 0, stream>>>(ST, SS);
        gemm_bf16<4><<<dim3(32, 2, nb), 256, 0, stream>>>(
            vB + (size_t)b0 * 256 * 4096, 4096, 256L * 4096,
            ST, 4096, SS, 4096,
            out + (size_t)b0 * 256 * 4096, 4096, 256L * 4096,
            nullptr, cv + (size_t)b0 * 256 * 4096, alpha, beta);
    }
}

// Round 4
// 275.761 us; speedup vs baseline: 7.8768x; 1.5936x over previous
//
#include <hip/hip_runtime.h>
#include <math.h>

#define NPIX 4096
#define CC   256

typedef __attribute__((ext_vector_type(8))) short bf16x8;
typedef __attribute__((ext_vector_type(8))) unsigned short u16x8;
typedef __attribute__((ext_vector_type(4))) float f32x4;

__device__ inline unsigned short f2bf(float f) {
    unsigned u = __builtin_bit_cast(unsigned, f);
    u += 0x7FFF + ((u >> 16) & 1);              // RTN-E
    return (unsigned short)(u >> 16);
}
__device__ inline float bf2f(unsigned short h) {
    unsigned u = (unsigned)h << 16;
    return __builtin_bit_cast(float, u);
}

// ---------------------------------------------------------------------------
// Weight prep: fp32 -> bf16; 3x3 weights reordered [O][C][3][3] -> [O][tap][C];
// merged q|k bias.
// ---------------------------------------------------------------------------
__global__ __launch_bounds__(256) void prep_kernel(
    const float* __restrict__ w2, const float* __restrict__ w3,
    const float* __restrict__ wq, const float* __restrict__ wk,
    const float* __restrict__ wv, const float* __restrict__ wb1,
    const float* __restrict__ wb2, const float* __restrict__ bq,
    const float* __restrict__ bk,
    unsigned short* w2b, unsigned short* w3b, unsigned short* wqb,
    unsigned short* wkb, unsigned short* wvb,
    unsigned short* wr1, unsigned short* wr2, float* bqk) {
    int i = blockIdx.x * 256 + threadIdx.x;
    if (i < 8192)  w2b[i] = f2bf(w2[i]);
    if (i < 32768) w3b[i] = f2bf(w3[i]);
    if (i < 65536) { wqb[i] = f2bf(wq[i]); wkb[i] = f2bf(wk[i]); wvb[i] = f2bf(wv[i]); }
    if (i < 256)   { bqk[i] = bq[i]; bqk[256 + i] = bk[i]; }
    if (i < 589824) {
        int o = i / 2304; int r = i - o * 2304; int tap = r >> 8; int c = r & 255;
        wr1[i] = f2bf(wb1[(o * 256 + c) * 9 + tap]);
        wr2[i] = f2bf(wb2[(o * 256 + c) * 9 + tap]);
    }
}

// ---------------------------------------------------------------------------
// Stem: x[b,3,p] fp32 -> h1T[b,p,64] bf16 (pixel-major), relu
// ---------------------------------------------------------------------------
__global__ __launch_bounds__(256) void stem1_kernel(
    const float* __restrict__ x, const float* __restrict__ w1,
    const float* __restrict__ b1, unsigned short* __restrict__ h1T) {
    int idx = blockIdx.x * 256 + threadIdx.x;   // b*2^18 + p*64 + o
    int o = idx & 63;
    int p = (idx >> 6) & 4095;
    int b = idx >> 18;
    const float* xb = x + (size_t)b * 3 * NPIX + p;
    float acc = b1[o];
    acc = fmaf(w1[o * 3 + 0], xb[0],        acc);
    acc = fmaf(w1[o * 3 + 1], xb[NPIX],     acc);
    acc = fmaf(w1[o * 3 + 2], xb[2 * NPIX], acc);
    h1T[idx] = f2bf(fmaxf(acc, 0.f));
}

// ---------------------------------------------------------------------------
// Unified bf16 MFMA GEMM: D[row][col] = sum_k A[row][k] * BT[col][k]
// 128x128 tile, BK=64, 4 waves (2x2), wave tile 64x64 (4x4 16x16x32 frags).
// EPI: 0 = store bf16(exp(acc)) + COLUMN-sum partials of the stored values
//          -> aux[z][by][rowhalf][col]  (S-GEMM; softmax denom is per col n)
//      1 = bf16, +bias[col], relu      (pixel-major 1x1 conv)
//      2 = bf16, +bias[col]            (q|k merged)
//      3 = bf16, (acc+bias[row]) * aux[z][col]   (v scaled by 1/D[n])
//      4 = f32,  alpha*CV + beta*acc   (PV + final combine, pure GEMM)
// ---------------------------------------------------------------------------
template<int EPI>
__global__ __launch_bounds__(256) void gemm_bf16(
    const unsigned short* __restrict__ A, long lda, long sA,
    const unsigned short* __restrict__ BT, long ldb, long sB,
    int K,
    void* __restrict__ Cp, long ldc, long sC,
    const float* __restrict__ bias,
    const float* __restrict__ CV,
    const float* __restrict__ alphaP, const float* __restrict__ betaP,
    float* __restrict__ aux) {
    constexpr int LDK = 72;                     // 64 + 8 pad
    __shared__ unsigned short As[128 * LDK];
    __shared__ unsigned short Bs[128 * LDK];
    const int tid  = threadIdx.x;
    const int lane = tid & 63;
    const int wave = tid >> 6;
    const int wr = (wave >> 1) * 64, wc = (wave & 1) * 64;
    const int l15 = lane & 15, lh = lane >> 4;
    const int z = blockIdx.z;
    const unsigned short* Ab = A  + (size_t)z * sA + (size_t)blockIdx.y * 128 * lda;
    const unsigned short* Bb = BT + (size_t)z * sB + (size_t)blockIdx.x * 128 * ldb;

    f32x4 acc[4][4];
    #pragma unroll
    for (int i = 0; i < 4; ++i)
        #pragma unroll
        for (int j = 0; j < 4; ++j) { f32x4 zr = {0.f, 0.f, 0.f, 0.f}; acc[i][j] = zr; }

    for (int k0 = 0; k0 < K; k0 += 64) {
        #pragma unroll
        for (int t = 0; t < 4; ++t) {           // 1024 16B chunks per tile
            int q = t * 256 + tid;
            int r = q >> 3, c = (q & 7) * 8;
            *(int4*)&As[r * LDK + c] = *(const int4*)&Ab[(size_t)r * lda + k0 + c];
            *(int4*)&Bs[r * LDK + c] = *(const int4*)&Bb[(size_t)r * ldb + k0 + c];
        }
        __syncthreads();
        #pragma unroll
        for (int ks = 0; ks < 2; ++ks) {
            bf16x8 a[4], b[4];
            #pragma unroll
            for (int f = 0; f < 4; ++f) {
                a[f] = *(const bf16x8*)&As[(wr + f * 16 + l15) * LDK + ks * 32 + lh * 8];
                b[f] = *(const bf16x8*)&Bs[(wc + f * 16 + l15) * LDK + ks * 32 + lh * 8];
            }
            #pragma unroll
            for (int i = 0; i < 4; ++i)
                #pragma unroll
                for (int j = 0; j < 4; ++j)
                    acc[i][j] = __builtin_amdgcn_mfma_f32_16x16x32_bf16(
                        a[i], b[j], acc[i][j], 0, 0, 0);
        }
        __syncthreads();
    }

    const int row0 = blockIdx.y * 128 + wr;
    const int col0 = blockIdx.x * 128 + wc;
    if (EPI == 4) {
        float* OUT = (float*)Cp + (size_t)z * sC;
        const float* CVb = CV + (size_t)z * sC;
        const float al = alphaP[0], be = betaP[0];
        #pragma unroll
        for (int i = 0; i < 4; ++i)
            #pragma unroll
            for (int j = 0; j < 4; ++j) {
                int cgl = col0 + j * 16 + l15;
                #pragma unroll
                for (int q = 0; q < 4; ++q) {
                    int r = row0 + i * 16 + lh * 4 + q;
                    size_t o = (size_t)r * ldc + cgl;
                    OUT[o] = al * CVb[o] + be * acc[i][j][q];
                }
            }
    } else if (EPI == 0) {
        // store bf16(exp(S)); accumulate column sums (denominator is per col n)
        unsigned short* OUT = (unsigned short*)Cp + (size_t)z * sC;
        float cs[4] = {0.f, 0.f, 0.f, 0.f};
        #pragma unroll
        for (int i = 0; i < 4; ++i)
            #pragma unroll
            for (int j = 0; j < 4; ++j) {
                int cgl = col0 + j * 16 + l15;
                #pragma unroll
                for (int q = 0; q < 4; ++q) {
                    int r = row0 + i * 16 + lh * 4 + q;
                    unsigned short h = f2bf(__expf(acc[i][j][q]));
                    OUT[(size_t)r * ldc + cgl] = h;
                    cs[j] += bf2f(h);           // sum the ROUNDED numerator
                }
            }
        #pragma unroll
        for (int off = 16; off <= 32; off <<= 1)    // reduce over lh (rows)
            #pragma unroll
            for (int j = 0; j < 4; ++j)
                cs[j] += __shfl_xor(cs[j], off);
        if (lh == 0) {
            // partial per (row-block, wave row-half), full column index
            float* part = aux + (((size_t)z * 32 + blockIdx.y) * 2 + (wave >> 1)) * 4096;
            #pragma unroll
            for (int j = 0; j < 4; ++j)
                part[col0 + j * 16 + l15] = cs[j];
        }
    } else {
        unsigned short* OUT = (unsigned short*)Cp + (size_t)z * sC;
        #pragma unroll
        for (int i = 0; i < 4; ++i)
            #pragma unroll
            for (int j = 0; j < 4; ++j) {
                int cgl = col0 + j * 16 + l15;
                float bc = (EPI == 1 || EPI == 2) ? bias[cgl] : 0.f;
                float sc = (EPI == 3) ? aux[(size_t)z * 4096 + cgl] : 1.f;
                #pragma unroll
                for (int q = 0; q < 4; ++q) {
                    int r = row0 + i * 16 + lh * 4 + q;
                    float v = acc[i][j][q];
                    if (EPI == 3) v = (v + bias[r]) * sc;
                    else v += bc;
                    if (EPI == 1) v = fmaxf(v, 0.f);
                    OUT[(size_t)r * ldc + cgl] = f2bf(v);
                }
            }
    }
}

// ---------------------------------------------------------------------------
// rcp[z][n] = 1 / sum over 64 partials part[z][by][half][n]
// ---------------------------------------------------------------------------
__global__ __launch_bounds__(256) void recip_kernel(
    const float* __restrict__ part, float* __restrict__ rcp) {
    int idx = blockIdx.x * 256 + threadIdx.x;   // z*4096 + n
    int z = idx >> 12, n = idx & 4095;
    const float* pb = part + (size_t)z * 32 * 2 * 4096 + n;
    float s = 0.f;
    #pragma unroll 8
    for (int t = 0; t < 64; ++t) s += pb[(size_t)t * 4096];
    rcp[idx] = 1.f / s;
}

// ---------------------------------------------------------------------------
// 3x3 SAME conv as implicit MFMA GEMM (unchanged, verified round 2).
// ---------------------------------------------------------------------------
template<int PIXOUT>
__global__ __launch_bounds__(256) void conv3_bf16(
    const unsigned short* __restrict__ X, const unsigned short* __restrict__ Wr,
    const float* __restrict__ bias, void* __restrict__ Outp) {
    __shared__ unsigned short patch[264 * 72];
    __shared__ unsigned short wt[128 * 72];
    const int tid  = threadIdx.x;
    const int lane = tid & 63;
    const int wave = tid >> 6;
    const int l15 = lane & 15, lh = lane >> 4;
    const int h0 = blockIdx.x;
    const int oh = blockIdx.y;
    const int b  = blockIdx.z;
    const int wy = (wave >> 1) * 64, wx = (wave & 1) * 64;
    const int obase = PIXOUT ? wx : wy;
    const int pbase = PIXOUT ? wy : wx;
    const unsigned short* Xb  = X + (size_t)b * (NPIX * CC);
    const unsigned short* Wro = Wr + (size_t)oh * 128 * 2304;

    f32x4 acc[4][4];
    #pragma unroll
    for (int i = 0; i < 4; ++i)
        #pragma unroll
        for (int j = 0; j < 4; ++j) { f32x4 zr = {0.f, 0.f, 0.f, 0.f}; acc[i][j] = zr; }

    for (int cc0 = 0; cc0 < 256; cc0 += 64) {
        __syncthreads();
        #pragma unroll
        for (int t = 0; t < 9; ++t) {
            int q = t * 256 + tid;
            if (q < 2112) {
                int s = q >> 3, ch = (q & 7) * 8;
                int r = s / 66, w = s - r * 66;
                int hh = h0 * 2 - 1 + r, ww = w - 1;
                int4 v = make_int4(0, 0, 0, 0);
                if ((unsigned)hh < 64u && (unsigned)ww < 64u)
                    v = *(const int4*)&Xb[(size_t)(hh * 64 + ww) * 256 + cc0 + ch];
                *(int4*)&patch[s * 72 + ch] = v;
            }
        }
        for (int tap = 0; tap < 9; ++tap) {
            const int dy = tap / 3 - 1, dx = tap % 3 - 1;
            __syncthreads();
            #pragma unroll
            for (int t = 0; t < 4; ++t) {
                int q = t * 256 + tid;
                int o = q >> 3, ch = (q & 7) * 8;
                *(int4*)&wt[o * 72 + ch] =
                    *(const int4*)&Wro[(size_t)o * 2304 + tap * 256 + cc0 + ch];
            }
            __syncthreads();
            #pragma unroll
            for (int ks = 0; ks < 2; ++ks) {
                bf16x8 wf[4], pf[4];
                #pragma unroll
                for (int f = 0; f < 4; ++f) {
                    int o = obase + f * 16 + l15;
                    wf[f] = *(const bf16x8*)&wt[o * 72 + ks * 32 + lh * 8];
                    int p = pbase + f * 16 + l15;
                    int slot = ((p >> 6) + dy + 1) * 66 + (p & 63) + dx + 1;
                    pf[f] = *(const bf16x8*)&patch[slot * 72 + ks * 32 + lh * 8];
                }
                #pragma unroll
                for (int i = 0; i < 4; ++i)
                    #pragma unroll
                    for (int j = 0; j < 4; ++j) {
                        if (PIXOUT)
                            acc[i][j] = __builtin_amdgcn_mfma_f32_16x16x32_bf16(
                                pf[i], wf[j], acc[i][j], 0, 0, 0);
                        else
                            acc[i][j] = __builtin_amdgcn_mfma_f32_16x16x32_bf16(
                                wf[i], pf[j], acc[i][j], 0, 0, 0);
                    }
            }
        }
    }

    const int P0 = h0 * 128;
    if (PIXOUT) {
        unsigned short* O = (unsigned short*)Outp + (size_t)b * (NPIX * CC);
        #pragma unroll
        for (int i = 0; i < 4; ++i)
            #pragma unroll
            for (int j = 0; j < 4; ++j) {
                int o = oh * 128 + obase + j * 16 + l15;
                float bb = bias[o];
                #pragma unroll
                for (int q = 0; q < 4; ++q) {
                    int p = pbase + i * 16 + lh * 4 + q;
                    float v = fmaxf(acc[i][j][q] + bb, 0.f);
                    O[(size_t)(P0 + p) * CC + o] = f2bf(v);
                }
            }
    } else {
        float* O = (float*)Outp + (size_t)b * (CC * NPIX);
        #pragma unroll
        for (int i = 0; i < 4; ++i)
            #pragma unroll
            for (int j = 0; j < 4; ++j) {
                #pragma unroll
                for (int q = 0; q < 4; ++q) {
                    int o = oh * 128 + obase + i * 16 + lh * 4 + q;
                    int p = pbase + j * 16 + l15;
                    O[(size_t)o * NPIX + P0 + p] = acc[i][j][q] + bias[o];
                }
            }
    }
}

// ---------------------------------------------------------------------------
extern "C" void kernel_launch(void* const* d_in, const int* in_sizes, int n_in,
                              void* d_out, int out_size, void* d_ws, size_t ws_size,
                              hipStream_t stream) {
    const float* x   = (const float*)d_in[0];
    const float* w1  = (const float*)d_in[1];  const float* b1  = (const float*)d_in[2];
    const float* w2  = (const float*)d_in[3];  const float* b2  = (const float*)d_in[4];
    const float* w3  = (const float*)d_in[5];  const float* b3  = (const float*)d_in[6];
    const float* wb1 = (const float*)d_in[7];  const float* bb1 = (const float*)d_in[8];
    const float* wb2 = (const float*)d_in[9];  const float* bb2 = (const float*)d_in[10];
    const float* wq  = (const float*)d_in[11]; const float* bq  = (const float*)d_in[12];
    const float* wk  = (const float*)d_in[13]; const float* bk  = (const float*)d_in[14];
    const float* wv  = (const float*)d_in[15]; const float* bv  = (const float*)d_in[16];
    const float* alpha = (const float*)d_in[17];
    const float* beta  = (const float*)d_in[18];

    const size_t MB = 1 << 20;
    char* wsb = (char*)d_ws;
    unsigned short* h1T = (unsigned short*)(wsb + 0 * MB);   // [4][4096][64]
    unsigned short* h2T = (unsigned short*)(wsb + 2 * MB);   // [4][4096][128]
    unsigned short* x3T = (unsigned short*)(wsb + 6 * MB);   // [4][4096][256]
    unsigned short* qkT = (unsigned short*)(wsb + 14 * MB);  // [4][4096][512] (q|k)
    unsigned short* vB  = (unsigned short*)(wsb + 30 * MB);  // [nb][256][4096] (scaled V)
    unsigned short* t1T = (unsigned short*)(wsb + 38 * MB);  // [4][4096][256]
    float*          cv  = (float*)(wsb + 46 * MB);           // [4][256][4096] fp32
    unsigned short* w2b = (unsigned short*)(wsb + 62 * MB);
    unsigned short* w3b = w2b + 8192;
    unsigned short* wqb = w3b + 32768;
    unsigned short* wkb = wqb + 65536;    // contiguous after wqb -> merged q|k
    unsigned short* wvb = wkb + 65536;
    unsigned short* wr1 = wvb + 65536;
    unsigned short* wr2 = wr1 + 589824;
    float*          bqk  = (float*)(wsb + 65 * MB);          // [512]
    float*          part = (float*)(wsb + 66 * MB);          // [nb][32][2][4096]
    float*          rcp  = (float*)(wsb + 70 * MB);          // [nb][4096]
    unsigned short* ST   = (unsigned short*)(wsb + 71 * MB); // [nb][4096][4096] = exp(S)
    float* out = (float*)d_out;

    prep_kernel<<<2304, 256, 0, stream>>>(w2, w3, wq, wk, wv, wb1, wb2, bq, bk,
                                          w2b, w3b, wqb, wkb, wvb, wr1, wr2, bqk);
    stem1_kernel<<<4096, 256, 0, stream>>>(x, w1, b1, h1T);

    // conv2: h1T[4096][64] x w2b -> h2T[4096][128], relu
    gemm_bf16<1><<<dim3(1, 32, 4), 256, 0, stream>>>(
        h1T, 64, 4096L * 64, w2b, 64, 0, 64,
        h2T, 128, 4096L * 128, b2, nullptr, nullptr, nullptr, nullptr);
    // conv3: -> x3T[4096][256], relu
    gemm_bf16<1><<<dim3(2, 32, 4), 256, 0, stream>>>(
        h2T, 128, 4096L * 128, w3b, 128, 0, 128,
        x3T, 256, 4096L * 256, b3, nullptr, nullptr, nullptr, nullptr);
    // q|k merged (pixel-major, N=512)
    gemm_bf16<2><<<dim3(4, 32, 4), 256, 0, stream>>>(
        x3T, 256, 4096L * 256, wqb, 256, 0, 256,
        qkT, 512, 4096L * 512, bqk, nullptr, nullptr, nullptr, nullptr);
    // conv3x3 branch
    conv3_bf16<1><<<dim3(32, 2, 4), 256, 0, stream>>>(x3T, wr1, bb1, t1T);
    conv3_bf16<0><<<dim3(32, 2, 4), 256, 0, stream>>>(t1T, wr2, bb2, cv);

    // attention: EST = exp(Q.K^T) + column partials -> rcp[n] ->
    //            V' = (Wv x3 + bv) * rcp[n] -> out = alpha*cv + beta*V'.EST^T
    const long SS = 4096L * 4096;
    const size_t base = 71 * MB;
    int nb = 1;
    if (ws_size >= base + 4 * (size_t)SS * 2)      nb = 4;
    else if (ws_size >= base + 2 * (size_t)SS * 2) nb = 2;
    for (int b0 = 0; b0 < 4; b0 += nb) {
        gemm_bf16<0><<<dim3(32, 32, nb), 256, 0, stream>>>(
            qkT + (size_t)b0 * 4096 * 512, 512, 4096L * 512,
            qkT + (size_t)b0 * 4096 * 512 + 256, 512, 4096L * 512,
            256, ST, 4096, SS, nullptr, nullptr, nullptr, nullptr, part);
        recip_kernel<<<nb * 16, 256, 0, stream>>>(part, rcp);
        // v (channel-major), scaled by rcp[n]: A = wvb [256][256] (sA=0)
        gemm_bf16<3><<<dim3(32, 2, nb), 256, 0, stream>>>(
            wvb, 256, 0,
            x3T + (size_t)b0 * 4096 * 256, 256, 4096L * 256, 256,
            vB, 4096, 256L * 4096, bv, nullptr, nullptr, nullptr, rcp);
        // PV: pure GEMM, combine with conv branch
        gemm_bf16<4><<<dim3(32, 2, nb), 256, 0, stream>>>(
            vB, 4096, 256L * 4096,
            ST, 4096, SS, 4096,
            out + (size_t)b0 * 256 * 4096, 4096, 256L * 4096,
            nullptr, cv + (size_t)b0 * 256 * 4096, alpha, beta, nullptr);
    }
}

// Round 5
// 265.275 us; speedup vs baseline: 8.1881x; 1.0395x over previous
//
#include <hip/hip_runtime.h>
#include <math.h>

#define NPIX 4096
#define CC   256

typedef __attribute__((ext_vector_type(8))) short bf16x8;
typedef __attribute__((ext_vector_type(4))) float f32x4;

__device__ inline unsigned short f2bf(float f) {
    unsigned u = __builtin_bit_cast(unsigned, f);
    u += 0x7FFF + ((u >> 16) & 1);              // RTN-E
    return (unsigned short)(u >> 16);
}
__device__ inline float bf2f(unsigned short h) {
    unsigned u = (unsigned)h << 16;
    return __builtin_bit_cast(float, u);
}
// async global->LDS, 16B per lane; LDS dest = wave-uniform base + lane*16
__device__ inline void gl_lds16(const unsigned short* g, unsigned short* l) {
    __builtin_amdgcn_global_load_lds(
        (const __attribute__((address_space(1))) void*)g,
        (__attribute__((address_space(3))) void*)l, 16, 0, 0);
}

// ---------------------------------------------------------------------------
// Weight prep: fp32 -> bf16; 3x3 weights reordered [O][C][3][3] -> [O][tap][C];
// merged q|k bias.
// ---------------------------------------------------------------------------
__global__ __launch_bounds__(256) void prep_kernel(
    const float* __restrict__ w2, const float* __restrict__ w3,
    const float* __restrict__ wq, const float* __restrict__ wk,
    const float* __restrict__ wv, const float* __restrict__ wb1,
    const float* __restrict__ wb2, const float* __restrict__ bq,
    const float* __restrict__ bk,
    unsigned short* w2b, unsigned short* w3b, unsigned short* wqb,
    unsigned short* wkb, unsigned short* wvb,
    unsigned short* wr1, unsigned short* wr2, float* bqk) {
    int i = blockIdx.x * 256 + threadIdx.x;
    if (i < 8192)  w2b[i] = f2bf(w2[i]);
    if (i < 32768) w3b[i] = f2bf(w3[i]);
    if (i < 65536) { wqb[i] = f2bf(wq[i]); wkb[i] = f2bf(wk[i]); wvb[i] = f2bf(wv[i]); }
    if (i < 256)   { bqk[i] = bq[i]; bqk[256 + i] = bk[i]; }
    if (i < 589824) {
        int o = i / 2304; int r = i - o * 2304; int tap = r >> 8; int c = r & 255;
        wr1[i] = f2bf(wb1[(o * 256 + c) * 9 + tap]);
        wr2[i] = f2bf(wb2[(o * 256 + c) * 9 + tap]);
    }
}

// ---------------------------------------------------------------------------
// Stem: x[b,3,p] fp32 -> h1T[b,p,64] bf16 (pixel-major), relu
// ---------------------------------------------------------------------------
__global__ __launch_bounds__(256) void stem1_kernel(
    const float* __restrict__ x, const float* __restrict__ w1,
    const float* __restrict__ b1, unsigned short* __restrict__ h1T) {
    int idx = blockIdx.x * 256 + threadIdx.x;   // b*2^18 + p*64 + o
    int o = idx & 63;
    int p = (idx >> 6) & 4095;
    int b = idx >> 18;
    const float* xb = x + (size_t)b * 3 * NPIX + p;
    float acc = b1[o];
    acc = fmaf(w1[o * 3 + 0], xb[0],        acc);
    acc = fmaf(w1[o * 3 + 1], xb[NPIX],     acc);
    acc = fmaf(w1[o * 3 + 2], xb[2 * NPIX], acc);
    h1T[idx] = f2bf(fmaxf(acc, 0.f));
}

// ---------------------------------------------------------------------------
// Unified bf16 MFMA GEMM: D[row][col] = sum_k A[row][k] * BT[col][k]
// 128x128 tile, BK=64, 4 waves (2x2), wave tile 64x64 (4x4 16x16x32 frags).
// Staging: global_load_lds 16B/lane into LINEAR [128][64] LDS with XOR
// slot swizzle (slot ^= row&7) applied on the GLOBAL source and on the
// fragment READ (both-sides involution) -> 2-way-free bank pattern.
// EPI: 0 = store bf16(exp(acc)) + COLUMN-sum partials -> aux (S-GEMM)
//      1 = bf16, +bias[col], relu      (pixel-major 1x1 conv)
//      2 = bf16, +bias[col]            (q|k merged)
//      3 = bf16, (acc+bias[row]) * aux[z][col]   (v scaled by 1/D[n])
//      4 = f32,  alpha*CV(bf16) + beta*acc   (PV + final combine)
// ---------------------------------------------------------------------------
template<int EPI>
__global__ __launch_bounds__(256) void gemm_bf16(
    const unsigned short* __restrict__ A, long lda, long sA,
    const unsigned short* __restrict__ BT, long ldb, long sB,
    int K,
    void* __restrict__ Cp, long ldc, long sC,
    const float* __restrict__ bias,
    const void* __restrict__ CV,
    const float* __restrict__ alphaP, const float* __restrict__ betaP,
    float* __restrict__ aux) {
    __shared__ unsigned short As[128 * 64];
    __shared__ unsigned short Bs[128 * 64];
    const int tid  = threadIdx.x;
    const int lane = tid & 63;
    const int wave = tid >> 6;
    const int wr = (wave >> 1) * 64, wc = (wave & 1) * 64;
    const int l15 = lane & 15, lh = lane >> 4;
    const int rowg = lane >> 3;                 // 0..7 (staging row within group)
    const int sl   = lane & 7;                  // staging slot
    const int z = blockIdx.z;
    const unsigned short* Ab = A  + (size_t)z * sA + (size_t)blockIdx.y * 128 * lda;
    const unsigned short* Bb = BT + (size_t)z * sB + (size_t)blockIdx.x * 128 * ldb;

    f32x4 acc[4][4];
    #pragma unroll
    for (int i = 0; i < 4; ++i)
        #pragma unroll
        for (int j = 0; j < 4; ++j) { f32x4 zr = {0.f, 0.f, 0.f, 0.f}; acc[i][j] = zr; }

    for (int k0 = 0; k0 < K; k0 += 64) {
        #pragma unroll
        for (int i = 0; i < 4; ++i) {           // 8 rows per wave per instr
            int rb  = wave * 8 + i * 32;
            int row = rb + rowg;
            int csw = (sl ^ (row & 7)) << 3;    // pre-swizzled source column
            gl_lds16(Ab + (size_t)row * lda + k0 + csw, &As[rb << 6]);
            gl_lds16(Bb + (size_t)row * ldb + k0 + csw, &Bs[rb << 6]);
        }
        __syncthreads();
        #pragma unroll
        for (int ks = 0; ks < 2; ++ks) {
            bf16x8 a[4], b[4];
            const int sa = (((ks << 2) + lh) ^ (l15 & 7)) << 3;   // swizzled read
            #pragma unroll
            for (int f = 0; f < 4; ++f) {
                a[f] = *(const bf16x8*)&As[((wr + f * 16 + l15) << 6) + sa];
                b[f] = *(const bf16x8*)&Bs[((wc + f * 16 + l15) << 6) + sa];
            }
            #pragma unroll
            for (int i = 0; i < 4; ++i)
                #pragma unroll
                for (int j = 0; j < 4; ++j)
                    acc[i][j] = __builtin_amdgcn_mfma_f32_16x16x32_bf16(
                        a[i], b[j], acc[i][j], 0, 0, 0);
        }
        __syncthreads();
    }

    const int row0 = blockIdx.y * 128 + wr;
    const int col0 = blockIdx.x * 128 + wc;
    if (EPI == 4) {
        float* OUT = (float*)Cp + (size_t)z * sC;
        const unsigned short* CVb = (const unsigned short*)CV + (size_t)z * sC;
        const float al = alphaP[0], be = betaP[0];
        #pragma unroll
        for (int i = 0; i < 4; ++i)
            #pragma unroll
            for (int j = 0; j < 4; ++j) {
                int cgl = col0 + j * 16 + l15;
                #pragma unroll
                for (int q = 0; q < 4; ++q) {
                    int r = row0 + i * 16 + lh * 4 + q;
                    size_t o = (size_t)r * ldc + cgl;
                    OUT[o] = al * bf2f(CVb[o]) + be * acc[i][j][q];
                }
            }
    } else if (EPI == 0) {
        // store bf16(exp(S)); accumulate column sums (denominator is per col n)
        unsigned short* OUT = (unsigned short*)Cp + (size_t)z * sC;
        float cs[4] = {0.f, 0.f, 0.f, 0.f};
        #pragma unroll
        for (int i = 0; i < 4; ++i)
            #pragma unroll
            for (int j = 0; j < 4; ++j) {
                int cgl = col0 + j * 16 + l15;
                #pragma unroll
                for (int q = 0; q < 4; ++q) {
                    int r = row0 + i * 16 + lh * 4 + q;
                    unsigned short h = f2bf(__expf(acc[i][j][q]));
                    OUT[(size_t)r * ldc + cgl] = h;
                    cs[j] += bf2f(h);           // sum the ROUNDED numerator
                }
            }
        #pragma unroll
        for (int off = 16; off <= 32; off <<= 1)    // reduce over lh (rows)
            #pragma unroll
            for (int j = 0; j < 4; ++j)
                cs[j] += __shfl_xor(cs[j], off);
        if (lh == 0) {
            float* part = aux + (((size_t)z * 32 + blockIdx.y) * 2 + (wave >> 1)) * 4096;
            #pragma unroll
            for (int j = 0; j < 4; ++j)
                part[col0 + j * 16 + l15] = cs[j];
        }
    } else {
        unsigned short* OUT = (unsigned short*)Cp + (size_t)z * sC;
        #pragma unroll
        for (int i = 0; i < 4; ++i)
            #pragma unroll
            for (int j = 0; j < 4; ++j) {
                int cgl = col0 + j * 16 + l15;
                float bc = (EPI == 1 || EPI == 2) ? bias[cgl] : 0.f;
                float sc = (EPI == 3) ? aux[(size_t)z * 4096 + cgl] : 1.f;
                #pragma unroll
                for (int q = 0; q < 4; ++q) {
                    int r = row0 + i * 16 + lh * 4 + q;
                    float v = acc[i][j][q];
                    if (EPI == 3) v = (v + bias[r]) * sc;
                    else v += bc;
                    if (EPI == 1) v = fmaxf(v, 0.f);
                    OUT[(size_t)r * ldc + cgl] = f2bf(v);
                }
            }
    }
}

// ---------------------------------------------------------------------------
// rcp[z][n] = 1 / sum over 64 partials part[z][by][half][n]
// ---------------------------------------------------------------------------
__global__ __launch_bounds__(256) void recip_kernel(
    const float* __restrict__ part, float* __restrict__ rcp) {
    int idx = blockIdx.x * 256 + threadIdx.x;   // z*4096 + n
    int z = idx >> 12, n = idx & 4095;
    const float* pb = part + (size_t)z * 32 * 2 * 4096 + n;
    float s = 0.f;
    #pragma unroll 8
    for (int t = 0; t < 64; ++t) s += pb[(size_t)t * 4096];
    rcp[idx] = 1.f / s;
}

// ---------------------------------------------------------------------------
// 3x3 SAME conv as implicit MFMA GEMM (verified round 2).
// PIXOUT=1: out bf16 pixel-major [p][256], relu
// PIXOUT=0: out bf16 channel-major [256][p], no relu (cv for PV epilogue)
// ---------------------------------------------------------------------------
template<int PIXOUT>
__global__ __launch_bounds__(256) void conv3_bf16(
    const unsigned short* __restrict__ X, const unsigned short* __restrict__ Wr,
    const float* __restrict__ bias, void* __restrict__ Outp) {
    __shared__ unsigned short patch[264 * 72];
    __shared__ unsigned short wt[128 * 72];
    const int tid  = threadIdx.x;
    const int lane = tid & 63;
    const int wave = tid >> 6;
    const int l15 = lane & 15, lh = lane >> 4;
    const int h0 = blockIdx.x;
    const int oh = blockIdx.y;
    const int b  = blockIdx.z;
    const int wy = (wave >> 1) * 64, wx = (wave & 1) * 64;
    const int obase = PIXOUT ? wx : wy;
    const int pbase = PIXOUT ? wy : wx;
    const unsigned short* Xb  = X + (size_t)b * (NPIX * CC);
    const unsigned short* Wro = Wr + (size_t)oh * 128 * 2304;

    f32x4 acc[4][4];
    #pragma unroll
    for (int i = 0; i < 4; ++i)
        #pragma unroll
        for (int j = 0; j < 4; ++j) { f32x4 zr = {0.f, 0.f, 0.f, 0.f}; acc[i][j] = zr; }

    for (int cc0 = 0; cc0 < 256; cc0 += 64) {
        __syncthreads();
        #pragma unroll
        for (int t = 0; t < 9; ++t) {
            int q = t * 256 + tid;
            if (q < 2112) {
                int s = q >> 3, ch = (q & 7) * 8;
                int r = s / 66, w = s - r * 66;
                int hh = h0 * 2 - 1 + r, ww = w - 1;
                int4 v = make_int4(0, 0, 0, 0);
                if ((unsigned)hh < 64u && (unsigned)ww < 64u)
                    v = *(const int4*)&Xb[(size_t)(hh * 64 + ww) * 256 + cc0 + ch];
                *(int4*)&patch[s * 72 + ch] = v;
            }
        }
        for (int tap = 0; tap < 9; ++tap) {
            const int dy = tap / 3 - 1, dx = tap % 3 - 1;
            __syncthreads();
            #pragma unroll
            for (int t = 0; t < 4; ++t) {
                int q = t * 256 + tid;
                int o = q >> 3, ch = (q & 7) * 8;
                *(int4*)&wt[o * 72 + ch] =
                    *(const int4*)&Wro[(size_t)o * 2304 + tap * 256 + cc0 + ch];
            }
            __syncthreads();
            #pragma unroll
            for (int ks = 0; ks < 2; ++ks) {
                bf16x8 wf[4], pf[4];
                #pragma unroll
                for (int f = 0; f < 4; ++f) {
                    int o = obase + f * 16 + l15;
                    wf[f] = *(const bf16x8*)&wt[o * 72 + ks * 32 + lh * 8];
                    int p = pbase + f * 16 + l15;
                    int slot = ((p >> 6) + dy + 1) * 66 + (p & 63) + dx + 1;
                    pf[f] = *(const bf16x8*)&patch[slot * 72 + ks * 32 + lh * 8];
                }
                #pragma unroll
                for (int i = 0; i < 4; ++i)
                    #pragma unroll
                    for (int j = 0; j < 4; ++j) {
                        if (PIXOUT)
                            acc[i][j] = __builtin_amdgcn_mfma_f32_16x16x32_bf16(
                                pf[i], wf[j], acc[i][j], 0, 0, 0);
                        else
                            acc[i][j] = __builtin_amdgcn_mfma_f32_16x16x32_bf16(
                                wf[i], pf[j], acc[i][j], 0, 0, 0);
                    }
            }
        }
    }

    const int P0 = h0 * 128;
    if (PIXOUT) {
        unsigned short* O = (unsigned short*)Outp + (size_t)b * (NPIX * CC);
        #pragma unroll
        for (int i = 0; i < 4; ++i)
            #pragma unroll
            for (int j = 0; j < 4; ++j) {
                int o = oh * 128 + obase + j * 16 + l15;
                float bb = bias[o];
                #pragma unroll
                for (int q = 0; q < 4; ++q) {
                    int p = pbase + i * 16 + lh * 4 + q;
                    float v = fmaxf(acc[i][j][q] + bb, 0.f);
                    O[(size_t)(P0 + p) * CC + o] = f2bf(v);
                }
            }
    } else {
        unsigned short* O = (unsigned short*)Outp + (size_t)b * (CC * NPIX);
        #pragma unroll
        for (int i = 0; i < 4; ++i)
            #pragma unroll
            for (int j = 0; j < 4; ++j) {
                #pragma unroll
                for (int q = 0; q < 4; ++q) {
                    int o = oh * 128 + obase + i * 16 + lh * 4 + q;
                    int p = pbase + j * 16 + l15;
                    O[(size_t)o * NPIX + P0 + p] = f2bf(acc[i][j][q] + bias[o]);
                }
            }
    }
}

// ---------------------------------------------------------------------------
extern "C" void kernel_launch(void* const* d_in, const int* in_sizes, int n_in,
                              void* d_out, int out_size, void* d_ws, size_t ws_size,
                              hipStream_t stream) {
    const float* x   = (const float*)d_in[0];
    const float* w1  = (const float*)d_in[1];  const float* b1  = (const float*)d_in[2];
    const float* w2  = (const float*)d_in[3];  const float* b2  = (const float*)d_in[4];
    const float* w3  = (const float*)d_in[5];  const float* b3  = (const float*)d_in[6];
    const float* wb1 = (const float*)d_in[7];  const float* bb1 = (const float*)d_in[8];
    const float* wb2 = (const float*)d_in[9];  const float* bb2 = (const float*)d_in[10];
    const float* wq  = (const float*)d_in[11]; const float* bq  = (const float*)d_in[12];
    const float* wk  = (const float*)d_in[13]; const float* bk  = (const float*)d_in[14];
    const float* wv  = (const float*)d_in[15]; const float* bv  = (const float*)d_in[16];
    const float* alpha = (const float*)d_in[17];
    const float* beta  = (const float*)d_in[18];

    const size_t MB = 1 << 20;
    char* wsb = (char*)d_ws;
    unsigned short* h1T = (unsigned short*)(wsb + 0 * MB);   // [4][4096][64]
    unsigned short* h2T = (unsigned short*)(wsb + 2 * MB);   // [4][4096][128]
    unsigned short* x3T = (unsigned short*)(wsb + 6 * MB);   // [4][4096][256]
    unsigned short* qkT = (unsigned short*)(wsb + 14 * MB);  // [4][4096][512] (q|k)
    unsigned short* vB  = (unsigned short*)(wsb + 30 * MB);  // [nb][256][4096] (scaled V)
    unsigned short* t1T = (unsigned short*)(wsb + 38 * MB);  // [4][4096][256]
    unsigned short* cv  = (unsigned short*)(wsb + 46 * MB);  // [4][256][4096] bf16
    unsigned short* w2b = (unsigned short*)(wsb + 62 * MB);
    unsigned short* w3b = w2b + 8192;
    unsigned short* wqb = w3b + 32768;
    unsigned short* wkb = wqb + 65536;    // contiguous after wqb -> merged q|k
    unsigned short* wvb = wkb + 65536;
    unsigned short* wr1 = wvb + 65536;
    unsigned short* wr2 = wr1 + 589824;
    float*          bqk  = (float*)(wsb + 65 * MB);          // [512]
    float*          part = (float*)(wsb + 66 * MB);          // [nb][32][2][4096]
    float*          rcp  = (float*)(wsb + 70 * MB);          // [nb][4096]
    unsigned short* ST   = (unsigned short*)(wsb + 71 * MB); // [nb][4096][4096] = exp(S)
    float* out = (float*)d_out;

    prep_kernel<<<2304, 256, 0, stream>>>(w2, w3, wq, wk, wv, wb1, wb2, bq, bk,
                                          w2b, w3b, wqb, wkb, wvb, wr1, wr2, bqk);
    stem1_kernel<<<4096, 256, 0, stream>>>(x, w1, b1, h1T);

    // conv2: h1T[4096][64] x w2b -> h2T[4096][128], relu
    gemm_bf16<1><<<dim3(1, 32, 4), 256, 0, stream>>>(
        h1T, 64, 4096L * 64, w2b, 64, 0, 64,
        h2T, 128, 4096L * 128, b2, nullptr, nullptr, nullptr, nullptr);
    // conv3: -> x3T[4096][256], relu
    gemm_bf16<1><<<dim3(2, 32, 4), 256, 0, stream>>>(
        h2T, 128, 4096L * 128, w3b, 128, 0, 128,
        x3T, 256, 4096L * 256, b3, nullptr, nullptr, nullptr, nullptr);
    // q|k merged (pixel-major, N=512)
    gemm_bf16<2><<<dim3(4, 32, 4), 256, 0, stream>>>(
        x3T, 256, 4096L * 256, wqb, 256, 0, 256,
        qkT, 512, 4096L * 512, bqk, nullptr, nullptr, nullptr, nullptr);
    // conv3x3 branch
    conv3_bf16<1><<<dim3(32, 2, 4), 256, 0, stream>>>(x3T, wr1, bb1, t1T);
    conv3_bf16<0><<<dim3(32, 2, 4), 256, 0, stream>>>(t1T, wr2, bb2, cv);

    // attention: EST = exp(Q.K^T) + column partials -> rcp[n] ->
    //            V' = (Wv x3 + bv) * rcp[n] -> out = alpha*cv + beta*V'.EST^T
    const long SS = 4096L * 4096;
    const size_t base = 71 * MB;
    int nb = 1;
    if (ws_size >= base + 4 * (size_t)SS * 2)      nb = 4;
    else if (ws_size >= base + 2 * (size_t)SS * 2) nb = 2;
    for (int b0 = 0; b0 < 4; b0 += nb) {
        gemm_bf16<0><<<dim3(32, 32, nb), 256, 0, stream>>>(
            qkT + (size_t)b0 * 4096 * 512, 512, 4096L * 512,
            qkT + (size_t)b0 * 4096 * 512 + 256, 512, 4096L * 512,
            256, ST, 4096, SS, nullptr, nullptr, nullptr, nullptr, part);
        recip_kernel<<<nb * 16, 256, 0, stream>>>(part, rcp);
        // v (channel-major), scaled by rcp[n]: A = wvb [256][256] (sA=0)
        gemm_bf16<3><<<dim3(32, 2, nb), 256, 0, stream>>>(
            wvb, 256, 0,
            x3T + (size_t)b0 * 4096 * 256, 256, 4096L * 256, 256,
            vB, 4096, 256L * 4096, bv, nullptr, nullptr, nullptr, rcp);
        // PV: pure GEMM, combine with conv branch (cv bf16)
        gemm_bf16<4><<<dim3(32, 2, nb), 256, 0, stream>>>(
            vB, 4096, 256L * 4096,
            ST, 4096, SS, 4096,
            out + (size_t)b0 * 256 * 4096, 4096, 256L * 4096,
            nullptr, cv + (size_t)b0 * 256 * 4096, alpha, beta, nullptr);
    }
}

// Round 6
// 264.006 us; speedup vs baseline: 8.2275x; 1.0048x over previous
//
#include <hip/hip_runtime.h>
#include <math.h>

#define NPIX 4096
#define CC   256

typedef __attribute__((ext_vector_type(8))) short bf16x8;
typedef __attribute__((ext_vector_type(4))) float f32x4;

__device__ inline unsigned short f2bf(float f) {
    unsigned u = __builtin_bit_cast(unsigned, f);
    u += 0x7FFF + ((u >> 16) & 1);              // RTN-E
    return (unsigned short)(u >> 16);
}
__device__ inline float bf2f(unsigned short h) {
    unsigned u = (unsigned)h << 16;
    return __builtin_bit_cast(float, u);
}
// async global->LDS, 16B per lane; LDS dest = wave-uniform base + lane*16
__device__ inline void gl_lds16(const unsigned short* g, unsigned short* l) {
    __builtin_amdgcn_global_load_lds(
        (const __attribute__((address_space(1))) void*)g,
        (__attribute__((address_space(3))) void*)l, 16, 0, 0);
}

// ---------------------------------------------------------------------------
// Weight prep (unchanged, verified)
// ---------------------------------------------------------------------------
__global__ __launch_bounds__(256) void prep_kernel(
    const float* __restrict__ w2, const float* __restrict__ w3,
    const float* __restrict__ wq, const float* __restrict__ wk,
    const float* __restrict__ wv, const float* __restrict__ wb1,
    const float* __restrict__ wb2, const float* __restrict__ bq,
    const float* __restrict__ bk,
    unsigned short* w2b, unsigned short* w3b, unsigned short* wqb,
    unsigned short* wkb, unsigned short* wvb,
    unsigned short* wr1, unsigned short* wr2, float* bqk) {
    int i = blockIdx.x * 256 + threadIdx.x;
    if (i < 8192)  w2b[i] = f2bf(w2[i]);
    if (i < 32768) w3b[i] = f2bf(w3[i]);
    if (i < 65536) { wqb[i] = f2bf(wq[i]); wkb[i] = f2bf(wk[i]); wvb[i] = f2bf(wv[i]); }
    if (i < 256)   { bqk[i] = bq[i]; bqk[256 + i] = bk[i]; }
    if (i < 589824) {
        int o = i / 2304; int r = i - o * 2304; int tap = r >> 8; int c = r & 255;
        wr1[i] = f2bf(wb1[(o * 256 + c) * 9 + tap]);
        wr2[i] = f2bf(wb2[(o * 256 + c) * 9 + tap]);
    }
}

// ---------------------------------------------------------------------------
// Stem (unchanged, verified)
// ---------------------------------------------------------------------------
__global__ __launch_bounds__(256) void stem1_kernel(
    const float* __restrict__ x, const float* __restrict__ w1,
    const float* __restrict__ b1, unsigned short* __restrict__ h1T) {
    int idx = blockIdx.x * 256 + threadIdx.x;
    int o = idx & 63;
    int p = (idx >> 6) & 4095;
    int b = idx >> 18;
    const float* xb = x + (size_t)b * 3 * NPIX + p;
    float acc = b1[o];
    acc = fmaf(w1[o * 3 + 0], xb[0],        acc);
    acc = fmaf(w1[o * 3 + 1], xb[NPIX],     acc);
    acc = fmaf(w1[o * 3 + 2], xb[2 * NPIX], acc);
    h1T[idx] = f2bf(fmaxf(acc, 0.f));
}

// ---------------------------------------------------------------------------
// Full-K single-stage GEMM (K = 64/128/256): stage BOTH whole panels with one
// burst of global_load_lds (all latencies overlap), ONE barrier, straight MFMA.
// XOR slot swizzle on global source + fragment read (involution, rule #21).
// EPI: 0 = bf16(exp(acc)) store + column-sum partials -> aux (S-GEMM)
//      1 = bf16, +bias[col], relu      2 = bf16, +bias[col]
//      3 = bf16, (acc+bias[row]) * aux[z*4096+col]  (V scaled by 1/D[n])
// ---------------------------------------------------------------------------
template<int EPI, int KK>
__global__ __launch_bounds__(256) void gemm_fullk(
    const unsigned short* __restrict__ A, long lda, long sA,
    const unsigned short* __restrict__ BT, long ldb, long sB,
    void* __restrict__ Cp, long ldc, long sC,
    const float* __restrict__ bias, float* __restrict__ aux) {
    constexpr int SPR = KK / 8;                 // 16B slots per row
    constexpr int RPI = 64 / SPR;               // rows per gl_lds instr
    __shared__ unsigned short As[128 * KK];
    __shared__ unsigned short Bs[128 * KK];
    const int tid  = threadIdx.x;
    const int lane = tid & 63;
    const int wave = tid >> 6;
    const int wr = (wave >> 1) * 64, wc = (wave & 1) * 64;
    const int l15 = lane & 15, lh = lane >> 4;
    const int sl  = lane & (SPR - 1);
    const int rof = lane / SPR;
    const int z = blockIdx.z;
    const unsigned short* Ab = A  + (size_t)z * sA + (size_t)blockIdx.y * 128 * lda;
    const unsigned short* Bb = BT + (size_t)z * sB + (size_t)blockIdx.x * 128 * ldb;

    f32x4 acc[4][4];
    #pragma unroll
    for (int i = 0; i < 4; ++i)
        #pragma unroll
        for (int j = 0; j < 4; ++j) { f32x4 zr = {0.f, 0.f, 0.f, 0.f}; acc[i][j] = zr; }

    #pragma unroll
    for (int i = 0; i < KK / 16; ++i) {         // whole panels, one burst
        int r0  = wave * 32 + i * RPI;
        int row = r0 + rof;
        int cs  = (sl ^ (row & (SPR - 1))) * 8;
        gl_lds16(Ab + (size_t)row * lda + cs, &As[r0 * KK]);
        gl_lds16(Bb + (size_t)row * ldb + cs, &Bs[r0 * KK]);
    }
    __syncthreads();                            // ONE drain+barrier

    #pragma unroll
    for (int ks = 0; ks < KK / 32; ++ks) {
        bf16x8 a[4], b[4];
        #pragma unroll
        for (int f = 0; f < 4; ++f) {
            int ra = wr + f * 16 + l15;
            a[f] = *(const bf16x8*)&As[ra * KK + ((((ks << 2) + lh) ^ (ra & (SPR - 1))) << 3)];
            int rb = wc + f * 16 + l15;
            b[f] = *(const bf16x8*)&Bs[rb * KK + ((((ks << 2) + lh) ^ (rb & (SPR - 1))) << 3)];
        }
        #pragma unroll
        for (int i = 0; i < 4; ++i)
            #pragma unroll
            for (int j = 0; j < 4; ++j)
                acc[i][j] = __builtin_amdgcn_mfma_f32_16x16x32_bf16(
                    a[i], b[j], acc[i][j], 0, 0, 0);
    }

    const int row0 = blockIdx.y * 128 + wr;
    const int col0 = blockIdx.x * 128 + wc;
    if (EPI == 0) {
        unsigned short* OUT = (unsigned short*)Cp + (size_t)z * sC;
        float cs4[4] = {0.f, 0.f, 0.f, 0.f};
        #pragma unroll
        for (int i = 0; i < 4; ++i)
            #pragma unroll
            for (int j = 0; j < 4; ++j) {
                int cgl = col0 + j * 16 + l15;
                #pragma unroll
                for (int q = 0; q < 4; ++q) {
                    int r = row0 + i * 16 + lh * 4 + q;
                    unsigned short h = f2bf(__expf(acc[i][j][q]));
                    OUT[(size_t)r * ldc + cgl] = h;
                    cs4[j] += bf2f(h);          // sum the ROUNDED numerator
                }
            }
        #pragma unroll
        for (int off = 16; off <= 32; off <<= 1)
            #pragma unroll
            for (int j = 0; j < 4; ++j)
                cs4[j] += __shfl_xor(cs4[j], off);
        if (lh == 0) {
            float* part = aux + (((size_t)z * 32 + blockIdx.y) * 2 + (wave >> 1)) * 4096;
            #pragma unroll
            for (int j = 0; j < 4; ++j)
                part[col0 + j * 16 + l15] = cs4[j];
        }
    } else {
        unsigned short* OUT = (unsigned short*)Cp + (size_t)z * sC;
        #pragma unroll
        for (int i = 0; i < 4; ++i)
            #pragma unroll
            for (int j = 0; j < 4; ++j) {
                int cgl = col0 + j * 16 + l15;
                float bc = (EPI == 1 || EPI == 2) ? bias[cgl] : 0.f;
                float sc = (EPI == 3) ? aux[(size_t)z * 4096 + cgl] : 1.f;
                #pragma unroll
                for (int q = 0; q < 4; ++q) {
                    int r = row0 + i * 16 + lh * 4 + q;
                    float v = acc[i][j][q];
                    if (EPI == 3) v = (v + bias[r]) * sc;
                    else v += bc;
                    if (EPI == 1) v = fmaxf(v, 0.f);
                    OUT[(size_t)r * ldc + cgl] = f2bf(v);
                }
            }
    }
}

// ---------------------------------------------------------------------------
// PV GEMM: K=4096, split-K + double-buffered 2-phase prefetch (stage next tile
// BEFORE compute; one barrier/iter). splits==1 writes out directly (alpha*cv+
// beta*acc); splits>1 writes fp32 partials reduced by reduce_kernel.
// ---------------------------------------------------------------------------
__global__ __launch_bounds__(256) void gemm_pv(
    const unsigned short* __restrict__ A, long lda, long sA,
    const unsigned short* __restrict__ BT, long ldb, long sB,
    int Kc, int splits,
    float* __restrict__ outp, long ldc, long sC,
    float* __restrict__ partial,
    const unsigned short* __restrict__ CV,
    const float* __restrict__ alphaP, const float* __restrict__ betaP) {
    __shared__ unsigned short As[2][128 * 64];
    __shared__ unsigned short Bs[2][128 * 64];
    const int tid  = threadIdx.x;
    const int lane = tid & 63;
    const int wave = tid >> 6;
    const int wr = (wave >> 1) * 64, wc = (wave & 1) * 64;
    const int l15 = lane & 15, lh = lane >> 4;
    const int sl  = lane & 7, rof = lane >> 3;
    const int cb = blockIdx.y & 1, sp = blockIdx.y >> 1;
    const int z  = blockIdx.z;
    const unsigned short* Ab = A  + (size_t)z * sA + (size_t)cb * 128 * lda + (size_t)sp * Kc;
    const unsigned short* Bb = BT + (size_t)z * sB + (size_t)blockIdx.x * 128 * ldb + (size_t)sp * Kc;

    f32x4 acc[4][4];
    #pragma unroll
    for (int i = 0; i < 4; ++i)
        #pragma unroll
        for (int j = 0; j < 4; ++j) { f32x4 zr = {0.f, 0.f, 0.f, 0.f}; acc[i][j] = zr; }

    auto STAGE = [&](int buf, int k) {
        #pragma unroll
        for (int i = 0; i < 4; ++i) {
            int r0  = wave * 32 + i * 8;
            int row = r0 + rof;
            int cs  = (sl ^ (row & 7)) * 8;
            gl_lds16(Ab + (size_t)row * lda + k + cs, &As[buf][r0 * 64]);
            gl_lds16(Bb + (size_t)row * ldb + k + cs, &Bs[buf][r0 * 64]);
        }
    };

    STAGE(0, 0);
    __syncthreads();
    const int T = Kc >> 6;
    for (int t = 0; t < T; ++t) {
        const int cur = t & 1;
        if (t + 1 < T) STAGE(cur ^ 1, (t + 1) << 6);   // prefetch overlaps MFMA
        #pragma unroll
        for (int ks = 0; ks < 2; ++ks) {
            bf16x8 a[4], b[4];
            #pragma unroll
            for (int f = 0; f < 4; ++f) {
                int ra = wr + f * 16 + l15;
                a[f] = *(const bf16x8*)&As[cur][ra * 64 + ((((ks << 2) + lh) ^ (ra & 7)) << 3)];
                int rb = wc + f * 16 + l15;
                b[f] = *(const bf16x8*)&Bs[cur][rb * 64 + ((((ks << 2) + lh) ^ (rb & 7)) << 3)];
            }
            #pragma unroll
            for (int i = 0; i < 4; ++i)
                #pragma unroll
                for (int j = 0; j < 4; ++j)
                    acc[i][j] = __builtin_amdgcn_mfma_f32_16x16x32_bf16(
                        a[i], b[j], acc[i][j], 0, 0, 0);
        }
        __syncthreads();                        // drain prefetch + swap
    }

    if (splits == 1) {
        float* OUT = outp + (size_t)z * sC;
        const unsigned short* CVb = CV + (size_t)z * sC;
        const float al = alphaP[0], be = betaP[0];
        #pragma unroll
        for (int i = 0; i < 4; ++i)
            #pragma unroll
            for (int j = 0; j < 4; ++j) {
                int cgl = blockIdx.x * 128 + wc + j * 16 + l15;
                #pragma unroll
                for (int q = 0; q < 4; ++q) {
                    int r = cb * 128 + wr + i * 16 + lh * 4 + q;
                    size_t o = (size_t)r * ldc + cgl;
                    OUT[o] = al * bf2f(CVb[o]) + be * acc[i][j][q];
                }
            }
    } else {
        float* P = partial + ((size_t)sp * gridDim.z + z) * ((size_t)256 * 4096);
        #pragma unroll
        for (int i = 0; i < 4; ++i)
            #pragma unroll
            for (int j = 0; j < 4; ++j) {
                int cgl = blockIdx.x * 128 + wc + j * 16 + l15;
                #pragma unroll
                for (int q = 0; q < 4; ++q) {
                    int r = cb * 128 + wr + i * 16 + lh * 4 + q;
                    P[(size_t)r * 4096 + cgl] = acc[i][j][q];
                }
            }
    }
}

// ---------------------------------------------------------------------------
// reduce: out = alpha*cv + beta * sum_sp partial[sp]   (vectorized float4)
// ---------------------------------------------------------------------------
__global__ __launch_bounds__(256) void reduce_kernel(
    const float* __restrict__ partial, const unsigned short* __restrict__ cvb,
    const float* __restrict__ alphaP, const float* __restrict__ betaP,
    float* __restrict__ outp, int splits, long chunk) {
    long idx = ((long)blockIdx.x * 256 + threadIdx.x) * 4;
    if (idx >= chunk) return;
    float4 s = *(const float4*)&partial[idx];
    for (int sp = 1; sp < splits; ++sp) {
        float4 p = *(const float4*)&partial[(size_t)sp * chunk + idx];
        s.x += p.x; s.y += p.y; s.z += p.z; s.w += p.w;
    }
    ushort4 c4 = *(const ushort4*)&cvb[idx];
    const float al = alphaP[0], be = betaP[0];
    float4 r;
    r.x = al * bf2f(c4.x) + be * s.x;
    r.y = al * bf2f(c4.y) + be * s.y;
    r.z = al * bf2f(c4.z) + be * s.z;
    r.w = al * bf2f(c4.w) + be * s.w;
    *(float4*)&outp[idx] = r;
}

// ---------------------------------------------------------------------------
// rcp[z][n] = 1 / sum over 64 partials (unchanged, verified)
// ---------------------------------------------------------------------------
__global__ __launch_bounds__(256) void recip_kernel(
    const float* __restrict__ part, float* __restrict__ rcp) {
    int idx = blockIdx.x * 256 + threadIdx.x;
    int z = idx >> 12, n = idx & 4095;
    const float* pb = part + (size_t)z * 32 * 2 * 4096 + n;
    float s = 0.f;
    #pragma unroll 8
    for (int t = 0; t < 64; ++t) s += pb[(size_t)t * 4096];
    rcp[idx] = 1.f / s;
}

// ---------------------------------------------------------------------------
// 3x3 SAME conv as implicit MFMA GEMM (unchanged, verified round 2/5).
// ---------------------------------------------------------------------------
template<int PIXOUT>
__global__ __launch_bounds__(256) void conv3_bf16(
    const unsigned short* __restrict__ X, const unsigned short* __restrict__ Wr,
    const float* __restrict__ bias, void* __restrict__ Outp) {
    __shared__ unsigned short patch[264 * 72];
    __shared__ unsigned short wt[128 * 72];
    const int tid  = threadIdx.x;
    const int lane = tid & 63;
    const int wave = tid >> 6;
    const int l15 = lane & 15, lh = lane >> 4;
    const int h0 = blockIdx.x;
    const int oh = blockIdx.y;
    const int b  = blockIdx.z;
    const int wy = (wave >> 1) * 64, wx = (wave & 1) * 64;
    const int obase = PIXOUT ? wx : wy;
    const int pbase = PIXOUT ? wy : wx;
    const unsigned short* Xb  = X + (size_t)b * (NPIX * CC);
    const unsigned short* Wro = Wr + (size_t)oh * 128 * 2304;

    f32x4 acc[4][4];
    #pragma unroll
    for (int i = 0; i < 4; ++i)
        #pragma unroll
        for (int j = 0; j < 4; ++j) { f32x4 zr = {0.f, 0.f, 0.f, 0.f}; acc[i][j] = zr; }

    for (int cc0 = 0; cc0 < 256; cc0 += 64) {
        __syncthreads();
        #pragma unroll
        for (int t = 0; t < 9; ++t) {
            int q = t * 256 + tid;
            if (q < 2112) {
                int s = q >> 3, ch = (q & 7) * 8;
                int r = s / 66, w = s - r * 66;
                int hh = h0 * 2 - 1 + r, ww = w - 1;
                int4 v = make_int4(0, 0, 0, 0);
                if ((unsigned)hh < 64u && (unsigned)ww < 64u)
                    v = *(const int4*)&Xb[(size_t)(hh * 64 + ww) * 256 + cc0 + ch];
                *(int4*)&patch[s * 72 + ch] = v;
            }
        }
        for (int tap = 0; tap < 9; ++tap) {
            const int dy = tap / 3 - 1, dx = tap % 3 - 1;
            __syncthreads();
            #pragma unroll
            for (int t = 0; t < 4; ++t) {
                int q = t * 256 + tid;
                int o = q >> 3, ch = (q & 7) * 8;
                *(int4*)&wt[o * 72 + ch] =
                    *(const int4*)&Wro[(size_t)o * 2304 + tap * 256 + cc0 + ch];
            }
            __syncthreads();
            #pragma unroll
            for (int ks = 0; ks < 2; ++ks) {
                bf16x8 wf[4], pf[4];
                #pragma unroll
                for (int f = 0; f < 4; ++f) {
                    int o = obase + f * 16 + l15;
                    wf[f] = *(const bf16x8*)&wt[o * 72 + ks * 32 + lh * 8];
                    int p = pbase + f * 16 + l15;
                    int slot = ((p >> 6) + dy + 1) * 66 + (p & 63) + dx + 1;
                    pf[f] = *(const bf16x8*)&patch[slot * 72 + ks * 32 + lh * 8];
                }
                #pragma unroll
                for (int i = 0; i < 4; ++i)
                    #pragma unroll
                    for (int j = 0; j < 4; ++j) {
                        if (PIXOUT)
                            acc[i][j] = __builtin_amdgcn_mfma_f32_16x16x32_bf16(
                                pf[i], wf[j], acc[i][j], 0, 0, 0);
                        else
                            acc[i][j] = __builtin_amdgcn_mfma_f32_16x16x32_bf16(
                                wf[i], pf[j], acc[i][j], 0, 0, 0);
                    }
            }
        }
    }

    const int P0 = h0 * 128;
    if (PIXOUT) {
        unsigned short* O = (unsigned short*)Outp + (size_t)b * (NPIX * CC);
        #pragma unroll
        for (int i = 0; i < 4; ++i)
            #pragma unroll
            for (int j = 0; j < 4; ++j) {
                int o = oh * 128 + obase + j * 16 + l15;
                float bb = bias[o];
                #pragma unroll
                for (int q = 0; q < 4; ++q) {
                    int p = pbase + i * 16 + lh * 4 + q;
                    float v = fmaxf(acc[i][j][q] + bb, 0.f);
                    O[(size_t)(P0 + p) * CC + o] = f2bf(v);
                }
            }
    } else {
        unsigned short* O = (unsigned short*)Outp + (size_t)b * (CC * NPIX);
        #pragma unroll
        for (int i = 0; i < 4; ++i)
            #pragma unroll
            for (int j = 0; j < 4; ++j) {
                #pragma unroll
                for (int q = 0; q < 4; ++q) {
                    int o = oh * 128 + obase + i * 16 + lh * 4 + q;
                    int p = pbase + j * 16 + l15;
                    O[(size_t)o * NPIX + P0 + p] = f2bf(acc[i][j][q] + bias[o]);
                }
            }
    }
}

// ---------------------------------------------------------------------------
extern "C" void kernel_launch(void* const* d_in, const int* in_sizes, int n_in,
                              void* d_out, int out_size, void* d_ws, size_t ws_size,
                              hipStream_t stream) {
    const float* x   = (const float*)d_in[0];
    const float* w1  = (const float*)d_in[1];  const float* b1  = (const float*)d_in[2];
    const float* w2  = (const float*)d_in[3];  const float* b2  = (const float*)d_in[4];
    const float* w3  = (const float*)d_in[5];  const float* b3  = (const float*)d_in[6];
    const float* wb1 = (const float*)d_in[7];  const float* bb1 = (const float*)d_in[8];
    const float* wb2 = (const float*)d_in[9];  const float* bb2 = (const float*)d_in[10];
    const float* wq  = (const float*)d_in[11]; const float* bq  = (const float*)d_in[12];
    const float* wk  = (const float*)d_in[13]; const float* bk  = (const float*)d_in[14];
    const float* wv  = (const float*)d_in[15]; const float* bv  = (const float*)d_in[16];
    const float* alpha = (const float*)d_in[17];
    const float* beta  = (const float*)d_in[18];

    const size_t MB = 1 << 20;
    char* wsb = (char*)d_ws;
    unsigned short* h1T = (unsigned short*)(wsb + 0 * MB);   // [4][4096][64]
    unsigned short* h2T = (unsigned short*)(wsb + 2 * MB);   // [4][4096][128]
    unsigned short* x3T = (unsigned short*)(wsb + 6 * MB);   // [4][4096][256]
    unsigned short* qkT = (unsigned short*)(wsb + 14 * MB);  // [4][4096][512]
    unsigned short* vB  = (unsigned short*)(wsb + 30 * MB);  // [nb][256][4096]
    unsigned short* t1T = (unsigned short*)(wsb + 38 * MB);  // [4][4096][256]
    unsigned short* cv  = (unsigned short*)(wsb + 46 * MB);  // [4][256][4096] bf16
    unsigned short* w2b = (unsigned short*)(wsb + 62 * MB);
    unsigned short* w3b = w2b + 8192;
    unsigned short* wqb = w3b + 32768;
    unsigned short* wkb = wqb + 65536;
    unsigned short* wvb = wkb + 65536;
    unsigned short* wr1 = wvb + 65536;
    unsigned short* wr2 = wr1 + 589824;
    float*          bqk  = (float*)(wsb + 65 * MB);
    float*          part = (float*)(wsb + 66 * MB);          // [nb][32][2][4096]
    float*          rcp  = (float*)(wsb + 70 * MB);          // [nb][4096]
    unsigned short* ST   = (unsigned short*)(wsb + 71 * MB); // [nb][4096][4096]
    float* out = (float*)d_out;
    const long ONEM = (long)CC * NPIX;                       // 1,048,576

    prep_kernel<<<2304, 256, 0, stream>>>(w2, w3, wq, wk, wv, wb1, wb2, bq, bk,
                                          w2b, w3b, wqb, wkb, wvb, wr1, wr2, bqk);
    stem1_kernel<<<4096, 256, 0, stream>>>(x, w1, b1, h1T);

    // conv2 (K=64), conv3 (K=128), q|k (K=256) — full-K single-stage
    gemm_fullk<1, 64><<<dim3(1, 32, 4), 256, 0, stream>>>(
        h1T, 64, 4096L * 64, w2b, 64, 0,
        h2T, 128, 4096L * 128, b2, nullptr);
    gemm_fullk<1, 128><<<dim3(2, 32, 4), 256, 0, stream>>>(
        h2T, 128, 4096L * 128, w3b, 128, 0,
        x3T, 256, 4096L * 256, b3, nullptr);
    gemm_fullk<2, 256><<<dim3(4, 32, 4), 256, 0, stream>>>(
        x3T, 256, 4096L * 256, wqb, 256, 0,
        qkT, 512, 4096L * 512, bqk, nullptr);
    // conv3x3 branch
    conv3_bf16<1><<<dim3(32, 2, 4), 256, 0, stream>>>(x3T, wr1, bb1, t1T);
    conv3_bf16<0><<<dim3(32, 2, 4), 256, 0, stream>>>(t1T, wr2, bb2, cv);

    // workspace gating: ST needs 71MB + nb*32MB; PV split partials need
    // splits*nb*4MB on top.
    const long SS = 4096L * 4096;
    int nb = 1;
    if (ws_size >= (size_t)(71 + 4 * 32) * MB)      nb = 4;
    else if (ws_size >= (size_t)(71 + 2 * 32) * MB) nb = 2;
    const size_t partOff = (size_t)71 * MB + (size_t)nb * 32 * MB;
    float* pvpart = (float*)(wsb + partOff);
    size_t avail = (ws_size > partOff) ? ws_size - partOff : 0;
    int splits = (int)(avail / ((size_t)nb * 4 * MB));
    splits = splits >= 4 ? 4 : (splits >= 2 ? 2 : 1);

    for (int b0 = 0; b0 < 4; b0 += nb) {
        // EST = exp(Q.K^T), column-sum partials
        gemm_fullk<0, 256><<<dim3(32, 32, nb), 256, 0, stream>>>(
            qkT + (size_t)b0 * 4096 * 512, 512, 4096L * 512,
            qkT + (size_t)b0 * 4096 * 512 + 256, 512, 4096L * 512,
            ST, 4096, SS, nullptr, part);
        recip_kernel<<<nb * 16, 256, 0, stream>>>(part, rcp);
        // V' = (Wv x3 + bv) * rcp[n], channel-major
        gemm_fullk<3, 256><<<dim3(32, 2, nb), 256, 0, stream>>>(
            wvb, 256, 0,
            x3T + (size_t)b0 * 4096 * 256, 256, 4096L * 256,
            vB, 4096, 256L * 4096, bv, rcp);
        // PV (+ combine): split-K dbuf
        gemm_pv<<<dim3(32, 2 * splits, nb), 256, 0, stream>>>(
            vB, 4096, 256L * 4096, ST, 4096, SS, 4096 / splits, splits,
            out + (size_t)b0 * ONEM, 4096, ONEM, pvpart,
            cv + (size_t)b0 * ONEM, alpha, beta);
        if (splits > 1)
            reduce_kernel<<<nb * 1024, 256, 0, stream>>>(
                pvpart, cv + (size_t)b0 * ONEM, alpha, beta,
                out + (size_t)b0 * ONEM, splits, (long)nb * ONEM);
    }
}